// Round 2
// baseline (512.082 us; speedup 1.0000x reference)
//
#include <hip/hip_runtime.h>
#include <hip/hip_bf16.h>

typedef __attribute__((ext_vector_type(8))) short bf16x8;
typedef __attribute__((ext_vector_type(4))) float f32x4;
typedef __attribute__((ext_vector_type(4))) int i32x4;
typedef __attribute__((ext_vector_type(2))) unsigned int u32x2;

// RNE fp32 -> bf16 bits (inputs finite; no NaN handling needed)
__device__ __forceinline__ unsigned int f2bf(float f) {
    union { float f; unsigned int u; } v; v.f = f;
    unsigned int u = v.u;
    u += 0x7FFFu + ((u >> 16) & 1u);
    return u >> 16;
}

__device__ __forceinline__ int swz(int row, int byte_in_row) {
    // XOR-swizzle within a 128-byte row: spreads stride-128B column reads
    // across 8 distinct 16B bank groups (Guideline 4 / T2).
    return row * 128 + (byte_in_row ^ ((row & 7) << 4));
}

// C[M][N] = (X[M][K] fp32) * (W[N][K] int32-holding-int8)^T * scale + bias
// 128x128 tile, BK=64, 256 threads = 4 waves in 2x2, each wave 64x64 out.
__global__ __launch_bounds__(256) void qlinear_kernel(
    const float* __restrict__ X, const int* __restrict__ W,
    const float* __restrict__ wscale, const float* __restrict__ bias,
    float* __restrict__ out, int M, int N, int K)
{
    __shared__ unsigned char smem[32768];   // As: [0,16K) Bs: [16K,32K)

    const int t    = threadIdx.x;
    const int lane = t & 63;
    const int wid  = t >> 6;
    const int wr   = wid >> 1;   // wave row (0..1)
    const int wc   = wid & 1;    // wave col (0..1)

    const int ntn = N >> 7;
    const int bm  = blockIdx.x / ntn;
    const int bn  = blockIdx.x % ntn;
    const int NT  = K >> 6;      // number of 64-wide K tiles

    const float* Ab = X + (size_t)bm * 128 * K;
    const int*   Bb = W + (size_t)bn * 128 * K;

    // staging coordinates (identical pattern for A and B: 16 chunks/row of 16B)
    const int srow = t >> 4, sc4 = t & 15;

    f32x4 av[8];
    i32x4 bv[8];

    auto loadAB = [&](int kt) {
        const float* Ap = Ab + kt * 64 + sc4 * 4;
#pragma unroll
        for (int l = 0; l < 8; ++l)
            av[l] = *(const f32x4*)(Ap + (size_t)(srow + 16 * l) * K);
        const int* Bp = Bb + kt * 64 + sc4 * 4;
#pragma unroll
        for (int l = 0; l < 8; ++l)
            bv[l] = *(const i32x4*)(Bp + (size_t)(srow + 16 * l) * K);
    };

    auto writeAB = [&]() {
#pragma unroll
        for (int l = 0; l < 8; ++l) {
            const int row = srow + 16 * l;
            u32x2 pk;
            pk[0] = f2bf(av[l][0]) | (f2bf(av[l][1]) << 16);
            pk[1] = f2bf(av[l][2]) | (f2bf(av[l][3]) << 16);
            *(u32x2*)(smem + swz(row, sc4 * 8)) = pk;
        }
#pragma unroll
        for (int l = 0; l < 8; ++l) {
            const int row = srow + 16 * l;
            u32x2 pk;
            pk[0] = f2bf((float)bv[l][0]) | (f2bf((float)bv[l][1]) << 16);
            pk[1] = f2bf((float)bv[l][2]) | (f2bf((float)bv[l][3]) << 16);
            *(u32x2*)(smem + 16384 + swz(row, sc4 * 8)) = pk;
        }
    };

    f32x4 acc[4][4];
#pragma unroll
    for (int mi = 0; mi < 4; ++mi)
#pragma unroll
        for (int ni = 0; ni < 4; ++ni)
            acc[mi][ni] = (f32x4){0.f, 0.f, 0.f, 0.f};

    const int kbyte = (lane >> 4) * 16;       // k-byte offset within 64B half-row
    const int afr   = wr * 64 + (lane & 15);  // A fragment row base
    const int bfr   = wc * 64 + (lane & 15);  // B fragment row base

    loadAB(0);

    for (int kt = 0; kt < NT; ++kt) {
        writeAB();
        __syncthreads();
        if (kt + 1 < NT) loadAB(kt + 1);   // issue next tile's globals early
#pragma unroll
        for (int kk = 0; kk < 2; ++kk) {
            bf16x8 a[4], b[4];
#pragma unroll
            for (int mi = 0; mi < 4; ++mi)
                a[mi] = *(const bf16x8*)(smem + swz(afr + 16 * mi, kk * 64 + kbyte));
#pragma unroll
            for (int ni = 0; ni < 4; ++ni)
                b[ni] = *(const bf16x8*)(smem + 16384 + swz(bfr + 16 * ni, kk * 64 + kbyte));
#pragma unroll
            for (int mi = 0; mi < 4; ++mi)
#pragma unroll
                for (int ni = 0; ni < 4; ++ni)
                    acc[mi][ni] = __builtin_amdgcn_mfma_f32_16x16x32_bf16(
                        a[mi], b[ni], acc[mi][ni], 0, 0, 0);
        }
        __syncthreads();
    }

    // epilogue: out = acc*scale + bias ; C/D layout col=lane&15, row=(lane>>4)*4+i
    const float scale = *wscale;
    const int orow0 = bm * 128 + wr * 64 + ((lane >> 4) << 2);
    const int ocol0 = bn * 128 + wc * 64 + (lane & 15);
#pragma unroll
    for (int ni = 0; ni < 4; ++ni) {
        const int col = ocol0 + 16 * ni;
        const float bb = bias[col];
#pragma unroll
        for (int mi = 0; mi < 4; ++mi) {
            const int row0 = orow0 + 16 * mi;
#pragma unroll
            for (int i = 0; i < 4; ++i)
                out[(size_t)(row0 + i) * N + col] = acc[mi][ni][i] * scale + bb;
        }
    }
}

extern "C" void kernel_launch(void* const* d_in, const int* in_sizes, int n_in,
                              void* d_out, int out_size, void* d_ws, size_t ws_size,
                              hipStream_t stream) {
    const float* x      = (const float*)d_in[0];
    const int*   w      = (const int*)d_in[1];      // int inputs arrive as int32
    const float* wscale = (const float*)d_in[2];
    const float* bias   = (const float*)d_in[3];
    float*       out    = (float*)d_out;

    const int DOUT = in_sizes[3];
    const int DIN  = in_sizes[1] / DOUT;
    const int M    = in_sizes[0] / DIN;

    dim3 grid((M / 128) * (DOUT / 128));
    qlinear_kernel<<<grid, 256, 0, stream>>>(x, w, wscale, bias, out, M, DOUT, DIN);
}

// Round 3
// 444.602 us; speedup vs baseline: 1.1518x; 1.1518x over previous
//
#include <hip/hip_runtime.h>
#include <hip/hip_bf16.h>

typedef __attribute__((ext_vector_type(8))) short bf16x8;
typedef __attribute__((ext_vector_type(4))) float f32x4;
typedef __attribute__((ext_vector_type(4))) int i32x4;
typedef __attribute__((ext_vector_type(2))) unsigned int u32x2;
typedef __attribute__((ext_vector_type(4))) unsigned int u32x4;

// RNE fp32 -> bf16 bits (inputs finite; no NaN handling needed)
__device__ __forceinline__ unsigned int f2bf(float f) {
    union { float f; unsigned int u; } v; v.f = f;
    unsigned int u = v.u;
    u += 0x7FFFu + ((u >> 16) & 1u);
    return u >> 16;
}

__device__ __forceinline__ void gl_lds16(const void* gptr, void* lptr) {
    __builtin_amdgcn_global_load_lds(
        (const __attribute__((address_space(1))) unsigned int*)gptr,
        (__attribute__((address_space(3))) unsigned int*)lptr, 16, 0, 0);
}

// ---------- pre-pass converts ----------
__global__ __launch_bounds__(256) void convert_x_kernel(
    const float* __restrict__ x, unsigned short* __restrict__ xb, long long n8)
{
    long long i = (long long)blockIdx.x * blockDim.x + threadIdx.x;
    const long long stride = (long long)gridDim.x * blockDim.x;
    for (; i < n8; i += stride) {
        const f32x4* p = (const f32x4*)(x + i * 8);
        f32x4 v0 = p[0], v1 = p[1];
        u32x4 q;
        q[0] = f2bf(v0[0]) | (f2bf(v0[1]) << 16);
        q[1] = f2bf(v0[2]) | (f2bf(v0[3]) << 16);
        q[2] = f2bf(v1[0]) | (f2bf(v1[1]) << 16);
        q[3] = f2bf(v1[2]) | (f2bf(v1[3]) << 16);
        *(u32x4*)(xb + i * 8) = q;
    }
}

__global__ __launch_bounds__(256) void convert_w_kernel(
    const int* __restrict__ w, unsigned short* __restrict__ wb, long long n8)
{
    long long i = (long long)blockIdx.x * blockDim.x + threadIdx.x;
    const long long stride = (long long)gridDim.x * blockDim.x;
    for (; i < n8; i += stride) {
        const i32x4* p = (const i32x4*)(w + i * 8);
        i32x4 v0 = p[0], v1 = p[1];
        u32x4 q;   // int8 values are exact in bf16
        q[0] = f2bf((float)v0[0]) | (f2bf((float)v0[1]) << 16);
        q[1] = f2bf((float)v0[2]) | (f2bf((float)v0[3]) << 16);
        q[2] = f2bf((float)v1[0]) | (f2bf((float)v1[1]) << 16);
        q[3] = f2bf((float)v1[2]) | (f2bf((float)v1[3]) << 16);
        *(u32x4*)(wb + i * 8) = q;
    }
}

// ---------- main GEMM: C = A(bf16)[M][K] * B(bf16)[N][K]^T * scale + bias ----------
// m97 structure: 128x128 tile, BK=64, 4 waves (2x2), global_load_lds w=16,
// linear LDS, 2 barriers per K-step, XCD-swizzled blockIdx.
__global__ __launch_bounds__(256) void gemm_bf16_kernel(
    const unsigned short* __restrict__ A, const unsigned short* __restrict__ Bw,
    const float* __restrict__ wscale, const float* __restrict__ bias,
    float* __restrict__ out, int M, int N, int K)
{
    __shared__ unsigned short As[128 * 64];
    __shared__ unsigned short Bs[128 * 64];

    const int t    = threadIdx.x;
    const int lane = t & 63;
    const int wid  = t >> 6;
    const int wr   = wid >> 1;
    const int wc   = wid & 1;

    const int ntn = N >> 7;
    const int nwg = gridDim.x;
    int bid = blockIdx.x;
    if ((nwg & 7) == 0) {                       // XCD-aware swizzle (T1)
        const int cpx = nwg >> 3;
        bid = (bid & 7) * cpx + (bid >> 3);
    }
    const int bm = bid / ntn;
    const int bn = bid % ntn;
    const int NT = K >> 6;

    const char* Abase = (const char*)(A  + (size_t)bm * 128 * K);
    const char* Bbase = (const char*)(Bw + (size_t)bn * 128 * K);
    const size_t rowb = (size_t)K * 2;

    // staging geometry: wave w, iter i covers rows [i*32+w*8, +8), lane->row l>>3, byte (l&7)*16
    const int srow_in = wid * 8 + (lane >> 3);
    const int scolb   = (lane & 7) * 16;
    const int sldsrow = wid * 8;                 // uniform per wave

    f32x4 acc[4][4];
#pragma unroll
    for (int mi = 0; mi < 4; ++mi)
#pragma unroll
        for (int ni = 0; ni < 4; ++ni)
            acc[mi][ni] = (f32x4){0.f, 0.f, 0.f, 0.f};

    const int kbyte = (lane >> 4) * 16;
    const int afr   = wr * 64 + (lane & 15);
    const int bfr   = wc * 64 + (lane & 15);

    for (int kt = 0; kt < NT; ++kt) {
        const char* Ag = Abase + (size_t)kt * 128;
        const char* Bg = Bbase + (size_t)kt * 128;
#pragma unroll
        for (int i = 0; i < 4; ++i) {
            const int r = i * 32 + srow_in;
            const int lr = i * 32 + sldsrow;
            gl_lds16(Ag + (size_t)r * rowb + scolb, (char*)As + lr * 128);
            gl_lds16(Bg + (size_t)r * rowb + scolb, (char*)Bs + lr * 128);
        }
        __syncthreads();   // compiler drains vmcnt(0) before s_barrier
#pragma unroll
        for (int kk = 0; kk < 2; ++kk) {
            bf16x8 a[4], b[4];
#pragma unroll
            for (int mi = 0; mi < 4; ++mi)
                a[mi] = *(const bf16x8*)((const char*)As + (afr + 16 * mi) * 128 + kk * 64 + kbyte);
#pragma unroll
            for (int ni = 0; ni < 4; ++ni)
                b[ni] = *(const bf16x8*)((const char*)Bs + (bfr + 16 * ni) * 128 + kk * 64 + kbyte);
#pragma unroll
            for (int mi = 0; mi < 4; ++mi)
#pragma unroll
                for (int ni = 0; ni < 4; ++ni)
                    acc[mi][ni] = __builtin_amdgcn_mfma_f32_16x16x32_bf16(
                        a[mi], b[ni], acc[mi][ni], 0, 0, 0);
        }
        __syncthreads();
    }

    const float scale = *wscale;
    const int orow0 = bm * 128 + wr * 64 + ((lane >> 4) << 2);
    const int ocol0 = bn * 128 + wc * 64 + (lane & 15);
#pragma unroll
    for (int ni = 0; ni < 4; ++ni) {
        const int col = ocol0 + 16 * ni;
        const float bb = bias[col];
#pragma unroll
        for (int mi = 0; mi < 4; ++mi) {
            const int row0 = orow0 + 16 * mi;
#pragma unroll
            for (int i = 0; i < 4; ++i)
                out[(size_t)(row0 + i) * N + col] = acc[mi][ni][i] * scale + bb;
        }
    }
}

// ---------- fallback: round-2 fused kernel (kept verbatim; passes) ----------
__device__ __forceinline__ int swz(int row, int byte_in_row) {
    return row * 128 + (byte_in_row ^ ((row & 7) << 4));
}

__global__ __launch_bounds__(256) void qlinear_fused_kernel(
    const float* __restrict__ X, const int* __restrict__ W,
    const float* __restrict__ wscale, const float* __restrict__ bias,
    float* __restrict__ out, int M, int N, int K)
{
    __shared__ unsigned char smem[32768];

    const int t    = threadIdx.x;
    const int lane = t & 63;
    const int wid  = t >> 6;
    const int wr   = wid >> 1;
    const int wc   = wid & 1;

    const int ntn = N >> 7;
    const int bm  = blockIdx.x / ntn;
    const int bn  = blockIdx.x % ntn;
    const int NT  = K >> 6;

    const float* Ab = X + (size_t)bm * 128 * K;
    const int*   Bb = W + (size_t)bn * 128 * K;

    const int srow = t >> 4, sc4 = t & 15;

    f32x4 av[8];
    i32x4 bv[8];

    auto loadAB = [&](int kt) {
        const float* Ap = Ab + kt * 64 + sc4 * 4;
#pragma unroll
        for (int l = 0; l < 8; ++l)
            av[l] = *(const f32x4*)(Ap + (size_t)(srow + 16 * l) * K);
        const int* Bp = Bb + kt * 64 + sc4 * 4;
#pragma unroll
        for (int l = 0; l < 8; ++l)
            bv[l] = *(const i32x4*)(Bp + (size_t)(srow + 16 * l) * K);
    };

    auto writeAB = [&]() {
#pragma unroll
        for (int l = 0; l < 8; ++l) {
            const int row = srow + 16 * l;
            u32x2 pk;
            pk[0] = f2bf(av[l][0]) | (f2bf(av[l][1]) << 16);
            pk[1] = f2bf(av[l][2]) | (f2bf(av[l][3]) << 16);
            *(u32x2*)(smem + swz(row, sc4 * 8)) = pk;
        }
#pragma unroll
        for (int l = 0; l < 8; ++l) {
            const int row = srow + 16 * l;
            u32x2 pk;
            pk[0] = f2bf((float)bv[l][0]) | (f2bf((float)bv[l][1]) << 16);
            pk[1] = f2bf((float)bv[l][2]) | (f2bf((float)bv[l][3]) << 16);
            *(u32x2*)(smem + 16384 + swz(row, sc4 * 8)) = pk;
        }
    };

    f32x4 acc[4][4];
#pragma unroll
    for (int mi = 0; mi < 4; ++mi)
#pragma unroll
        for (int ni = 0; ni < 4; ++ni)
            acc[mi][ni] = (f32x4){0.f, 0.f, 0.f, 0.f};

    const int kbyte = (lane >> 4) * 16;
    const int afr   = wr * 64 + (lane & 15);
    const int bfr   = wc * 64 + (lane & 15);

    loadAB(0);

    for (int kt = 0; kt < NT; ++kt) {
        writeAB();
        __syncthreads();
        if (kt + 1 < NT) loadAB(kt + 1);
#pragma unroll
        for (int kk = 0; kk < 2; ++kk) {
            bf16x8 a[4], b[4];
#pragma unroll
            for (int mi = 0; mi < 4; ++mi)
                a[mi] = *(const bf16x8*)(smem + swz(afr + 16 * mi, kk * 64 + kbyte));
#pragma unroll
            for (int ni = 0; ni < 4; ++ni)
                b[ni] = *(const bf16x8*)(smem + 16384 + swz(bfr + 16 * ni, kk * 64 + kbyte));
#pragma unroll
            for (int mi = 0; mi < 4; ++mi)
#pragma unroll
                for (int ni = 0; ni < 4; ++ni)
                    acc[mi][ni] = __builtin_amdgcn_mfma_f32_16x16x32_bf16(
                        a[mi], b[ni], acc[mi][ni], 0, 0, 0);
        }
        __syncthreads();
    }

    const float scale = *wscale;
    const int orow0 = bm * 128 + wr * 64 + ((lane >> 4) << 2);
    const int ocol0 = bn * 128 + wc * 64 + (lane & 15);
#pragma unroll
    for (int ni = 0; ni < 4; ++ni) {
        const int col = ocol0 + 16 * ni;
        const float bb = bias[col];
#pragma unroll
        for (int mi = 0; mi < 4; ++mi) {
            const int row0 = orow0 + 16 * mi;
#pragma unroll
            for (int i = 0; i < 4; ++i)
                out[(size_t)(row0 + i) * N + col] = acc[mi][ni][i] * scale + bb;
        }
    }
}

extern "C" void kernel_launch(void* const* d_in, const int* in_sizes, int n_in,
                              void* d_out, int out_size, void* d_ws, size_t ws_size,
                              hipStream_t stream) {
    const float* x      = (const float*)d_in[0];
    const int*   w      = (const int*)d_in[1];      // int inputs arrive as int32
    const float* wscale = (const float*)d_in[2];
    const float* bias   = (const float*)d_in[3];
    float*       out    = (float*)d_out;

    const int DOUT = in_sizes[3];
    const int DIN  = in_sizes[1] / DOUT;
    const int M    = in_sizes[0] / DIN;

    const size_t xb_bytes = (size_t)M * DIN * 2;
    const size_t wb_bytes = (size_t)DOUT * DIN * 2;

    if (ws_size >= xb_bytes + wb_bytes) {
        unsigned short* xb = (unsigned short*)d_ws;
        unsigned short* wb = (unsigned short*)((char*)d_ws + xb_bytes);

        const long long nx8 = (long long)M * DIN / 8;
        const long long nw8 = (long long)DOUT * DIN / 8;
        convert_x_kernel<<<2048, 256, 0, stream>>>(x, xb, nx8);
        convert_w_kernel<<<2048, 256, 0, stream>>>(w, wb, nw8);

        dim3 grid((M / 128) * (DOUT / 128));
        gemm_bf16_kernel<<<grid, 256, 0, stream>>>(xb, wb, wscale, bias, out, M, DOUT, DIN);
    } else {
        dim3 grid((M / 128) * (DOUT / 128));
        qlinear_fused_kernel<<<grid, 256, 0, stream>>>(x, w, wscale, bias, out, M, DOUT, DIN);
    }
}

// Round 4
// 316.681 us; speedup vs baseline: 1.6170x; 1.4039x over previous
//
#include <hip/hip_runtime.h>
#include <hip/hip_bf16.h>

typedef __attribute__((ext_vector_type(8))) short bf16x8;
typedef __attribute__((ext_vector_type(4))) float f32x4;
typedef __attribute__((ext_vector_type(4))) int i32x4;
typedef __attribute__((ext_vector_type(2))) unsigned int u32x2;
typedef __attribute__((ext_vector_type(4))) unsigned int u32x4;

// RNE fp32 -> bf16 bits (inputs finite; no NaN handling needed)
__device__ __forceinline__ unsigned int f2bf(float f) {
    union { float f; unsigned int u; } v; v.f = f;
    unsigned int u = v.u;
    u += 0x7FFFu + ((u >> 16) & 1u);
    return u >> 16;
}

__device__ __forceinline__ void gl_lds16(const void* gptr, void* lptr) {
    __builtin_amdgcn_global_load_lds(
        (const __attribute__((address_space(1))) unsigned int*)gptr,
        (__attribute__((address_space(3))) unsigned int*)lptr, 16, 0, 0);
}

// ---------- pre-pass converts ----------
__global__ __launch_bounds__(256) void convert_x_kernel(
    const float* __restrict__ x, unsigned short* __restrict__ xb, long long n8)
{
    long long i = (long long)blockIdx.x * blockDim.x + threadIdx.x;
    const long long stride = (long long)gridDim.x * blockDim.x;
    for (; i < n8; i += stride) {
        const f32x4* p = (const f32x4*)(x + i * 8);
        f32x4 v0 = p[0], v1 = p[1];
        u32x4 q;
        q[0] = f2bf(v0[0]) | (f2bf(v0[1]) << 16);
        q[1] = f2bf(v0[2]) | (f2bf(v0[3]) << 16);
        q[2] = f2bf(v1[0]) | (f2bf(v1[1]) << 16);
        q[3] = f2bf(v1[2]) | (f2bf(v1[3]) << 16);
        *(u32x4*)(xb + i * 8) = q;
    }
}

__global__ __launch_bounds__(256) void convert_w_kernel(
    const int* __restrict__ w, unsigned short* __restrict__ wb, long long n8)
{
    long long i = (long long)blockIdx.x * blockDim.x + threadIdx.x;
    const long long stride = (long long)gridDim.x * blockDim.x;
    for (; i < n8; i += stride) {
        const i32x4* p = (const i32x4*)(w + i * 8);
        i32x4 v0 = p[0], v1 = p[1];
        u32x4 q;   // int8 values are exact in bf16
        q[0] = f2bf((float)v0[0]) | (f2bf((float)v0[1]) << 16);
        q[1] = f2bf((float)v0[2]) | (f2bf((float)v0[3]) << 16);
        q[2] = f2bf((float)v1[0]) | (f2bf((float)v1[1]) << 16);
        q[3] = f2bf((float)v1[2]) | (f2bf((float)v1[3]) << 16);
        *(u32x4*)(wb + i * 8) = q;
    }
}

// ---------- 256x256 8-phase GEMM: C = A[M][K] * B[N][K]^T * scale + bias ----------
// T1 XCD swizzle + T2 XOR-swizzled LDS (pre-swizzled global src, linear DMA dest)
// + T3/T4 phased schedule w/ deep prefetch + T5 setprio. 512 thr = 8 waves (2Mx4N).
__global__ __launch_bounds__(512, 2) void gemm256_kernel(
    const unsigned short* __restrict__ A, const unsigned short* __restrict__ Bw,
    const float* __restrict__ wscale, const float* __restrict__ bias,
    float* __restrict__ out, int M, int N, int K)
{
    // [2 dbuf][ A 32KB | B 32KB ] = 128 KiB
    __shared__ unsigned char lds[131072];

    const int tid  = threadIdx.x;
    const int lane = tid & 63;
    const int wid  = tid >> 6;
    const int wr   = wid >> 2;   // 0..1  -> 128 output rows
    const int wc   = wid & 3;    // 0..3  -> 64 output cols

    const int ntn = N >> 8;
    const int nwg = gridDim.x;
    int bid = blockIdx.x;
    if ((nwg & 7) == 0) {                       // XCD-aware swizzle (T1)
        const int cpx = nwg >> 3;
        bid = (bid & 7) * cpx + (bid >> 3);
    }
    const int bm = bid / ntn;
    const int bn = bid % ntn;
    const int NT = K >> 5 >> 1;                 // K / 64

    const char* Abase = (const char*)(A  + (size_t)bm * 256 * K);
    const char* Bbase = (const char*)(Bw + (size_t)bn * 256 * K);
    const size_t rowb = (size_t)K * 2;

    // stage geometry: per gl_lds, 512 thr x 16B = 64 rows x 128B (one quarter).
    // LDS dest is wave-linear; SOURCE column pre-swizzled so that LDS holds
    // (row, b) = global col b ^ ((row&7)<<4).   row&7 == lane>>3 here.
    const int s_row  = tid >> 3;                                  // 0..63
    const int s_colb = (((lane & 7) ^ (lane >> 3)) << 4);         // swizzled src col
    const int s_ldso = wid * 1024 + lane * 16;                    // within quarter

    auto stage = [&](int kt, int c) {
        const char* Ag = Abase + (size_t)kt * 128;
        const char* Bg = Bbase + (size_t)kt * 128;
        char* Al = (char*)lds + (c << 16);
        char* Bl = Al + 32768;
#pragma unroll
        for (int q = 0; q < 4; ++q)
            gl_lds16(Ag + (size_t)(q * 64 + s_row) * rowb + s_colb,
                     Al + q * 8192 + s_ldso);
#pragma unroll
        for (int q = 0; q < 4; ++q)
            gl_lds16(Bg + (size_t)(q * 64 + s_row) * rowb + s_colb,
                     Bl + q * 8192 + s_ldso);
    };

    // fragment-read offsets (swizzled): row&7 == lane&7 (row bases are x16)
    const int arow0 = (wr * 128 + (lane & 15)) * 128;
    const int brow0 = (wc * 64 + (lane & 15)) * 128;
    const int cswz0 = (((lane >> 4) * 16)      ) ^ ((lane & 7) << 4);
    const int cswz1 = (((lane >> 4) * 16) + 64 ) ^ ((lane & 7) << 4);

    f32x4 acc[8][4];
#pragma unroll
    for (int mi = 0; mi < 8; ++mi)
#pragma unroll
        for (int ni = 0; ni < 4; ++ni)
            acc[mi][ni] = (f32x4){0.f, 0.f, 0.f, 0.f};

    auto ldA = [&](const char* Al, int mh, int kk, bf16x8* a) {
        const int c = kk ? cswz1 : cswz0;
#pragma unroll
        for (int fm = 0; fm < 4; ++fm)
            a[fm] = *(const bf16x8*)(Al + arow0 + (mh * 64 + fm * 16) * 128 + c);
    };
    auto ldB = [&](const char* Bl, int kk, bf16x8* b) {
        const int c = kk ? cswz1 : cswz0;
#pragma unroll
        for (int fn = 0; fn < 4; ++fn)
            b[fn] = *(const bf16x8*)(Bl + brow0 + fn * 16 * 128 + c);
    };
    auto mm = [&](const bf16x8* a, const bf16x8* b, int mh) {
#pragma unroll
        for (int fm = 0; fm < 4; ++fm)
#pragma unroll
            for (int fn = 0; fn < 4; ++fn)
                acc[mh * 4 + fm][fn] = __builtin_amdgcn_mfma_f32_16x16x32_bf16(
                    a[fm], b[fn], acc[mh * 4 + fm][fn], 0, 0, 0);
    };

    // prologue: tile 0 -> buf 0
    stage(0, 0);
    asm volatile("s_waitcnt vmcnt(0)" ::: "memory");
    __builtin_amdgcn_sched_barrier(0);
    asm volatile("s_barrier" ::: "memory");

#pragma unroll 2
    for (int t = 0; t < NT; ++t) {
        const int c = t & 1;
        const char* Al = (const char*)lds + (c << 16);
        const char* Bl = Al + 32768;
        bf16x8 a[4], b[4];

        // phase 0 (mh=0, kk=0): deep prefetch of tile t+1 into idle buffer
        ldA(Al, 0, 0, a); ldB(Bl, 0, b);
        if (t + 1 < NT) stage(t + 1, c ^ 1);
        asm volatile("s_barrier" ::: "memory");
        __builtin_amdgcn_s_setprio(1); mm(a, b, 0); __builtin_amdgcn_s_setprio(0);
        asm volatile("s_barrier" ::: "memory");

        // phase 1 (mh=1, kk=0)
        ldA(Al, 1, 0, a);
        asm volatile("s_barrier" ::: "memory");
        __builtin_amdgcn_s_setprio(1); mm(a, b, 1); __builtin_amdgcn_s_setprio(0);
        asm volatile("s_barrier" ::: "memory");

        // phase 2 (mh=0, kk=1)
        ldA(Al, 0, 1, a); ldB(Bl, 1, b);
        asm volatile("s_barrier" ::: "memory");
        __builtin_amdgcn_s_setprio(1); mm(a, b, 0); __builtin_amdgcn_s_setprio(0);
        asm volatile("s_barrier" ::: "memory");

        // phase 3 (mh=1, kk=1); drain AFTER this phase's MFMA (max load cover)
        ldA(Al, 1, 1, a);
        asm volatile("s_barrier" ::: "memory");
        __builtin_amdgcn_s_setprio(1); mm(a, b, 1); __builtin_amdgcn_s_setprio(0);
        asm volatile("s_waitcnt vmcnt(0) lgkmcnt(0)" ::: "memory");
        __builtin_amdgcn_sched_barrier(0);
        asm volatile("s_barrier" ::: "memory");
    }

    // epilogue: out = acc*scale + bias ; C/D layout col=lane&15, row=(lane>>4)*4+i
    const float scale = *wscale;
    const int orow0 = bm * 256 + wr * 128 + ((lane >> 4) << 2);
    const int ocol0 = bn * 256 + wc * 64 + (lane & 15);
#pragma unroll
    for (int ni = 0; ni < 4; ++ni) {
        const int col = ocol0 + 16 * ni;
        const float bb = bias[col];
#pragma unroll
        for (int mi = 0; mi < 8; ++mi) {
            const int row0 = orow0 + (mi >> 2) * 64 + (mi & 3) * 16;
#pragma unroll
            for (int i = 0; i < 4; ++i)
                out[(size_t)(row0 + i) * N + col] = acc[mi][ni][i] * scale + bb;
        }
    }
}

// ---------- fallback: round-2 fused kernel (passes; used only if ws too small) ----------
__device__ __forceinline__ int swz(int row, int byte_in_row) {
    return row * 128 + (byte_in_row ^ ((row & 7) << 4));
}

__global__ __launch_bounds__(256) void qlinear_fused_kernel(
    const float* __restrict__ X, const int* __restrict__ W,
    const float* __restrict__ wscale, const float* __restrict__ bias,
    float* __restrict__ out, int M, int N, int K)
{
    __shared__ unsigned char smem[32768];

    const int t    = threadIdx.x;
    const int lane = t & 63;
    const int wid  = t >> 6;
    const int wr   = wid >> 1;
    const int wc   = wid & 1;

    const int ntn = N >> 7;
    const int bm  = blockIdx.x / ntn;
    const int bn  = blockIdx.x % ntn;
    const int NT  = K >> 6;

    const float* Ab = X + (size_t)bm * 128 * K;
    const int*   Bb = W + (size_t)bn * 128 * K;

    const int srow = t >> 4, sc4 = t & 15;

    f32x4 av[8];
    i32x4 bv[8];

    auto loadAB = [&](int kt) {
        const float* Ap = Ab + kt * 64 + sc4 * 4;
#pragma unroll
        for (int l = 0; l < 8; ++l)
            av[l] = *(const f32x4*)(Ap + (size_t)(srow + 16 * l) * K);
        const int* Bp = Bb + kt * 64 + sc4 * 4;
#pragma unroll
        for (int l = 0; l < 8; ++l)
            bv[l] = *(const i32x4*)(Bp + (size_t)(srow + 16 * l) * K);
    };

    auto writeAB = [&]() {
#pragma unroll
        for (int l = 0; l < 8; ++l) {
            const int row = srow + 16 * l;
            u32x2 pk;
            pk[0] = f2bf(av[l][0]) | (f2bf(av[l][1]) << 16);
            pk[1] = f2bf(av[l][2]) | (f2bf(av[l][3]) << 16);
            *(u32x2*)(smem + swz(row, sc4 * 8)) = pk;
        }
#pragma unroll
        for (int l = 0; l < 8; ++l) {
            const int row = srow + 16 * l;
            u32x2 pk;
            pk[0] = f2bf((float)bv[l][0]) | (f2bf((float)bv[l][1]) << 16);
            pk[1] = f2bf((float)bv[l][2]) | (f2bf((float)bv[l][3]) << 16);
            *(u32x2*)(smem + 16384 + swz(row, sc4 * 8)) = pk;
        }
    };

    f32x4 acc[4][4];
#pragma unroll
    for (int mi = 0; mi < 4; ++mi)
#pragma unroll
        for (int ni = 0; ni < 4; ++ni)
            acc[mi][ni] = (f32x4){0.f, 0.f, 0.f, 0.f};

    const int kbyte = (lane >> 4) * 16;
    const int afr   = wr * 64 + (lane & 15);
    const int bfr   = wc * 64 + (lane & 15);

    loadAB(0);

    for (int kt = 0; kt < NT; ++kt) {
        writeAB();
        __syncthreads();
        if (kt + 1 < NT) loadAB(kt + 1);
#pragma unroll
        for (int kk = 0; kk < 2; ++kk) {
            bf16x8 a[4], b[4];
#pragma unroll
            for (int mi = 0; mi < 4; ++mi)
                a[mi] = *(const bf16x8*)(smem + swz(afr + 16 * mi, kk * 64 + kbyte));
#pragma unroll
            for (int ni = 0; ni < 4; ++ni)
                b[ni] = *(const bf16x8*)(smem + 16384 + swz(bfr + 16 * ni, kk * 64 + kbyte));
#pragma unroll
            for (int mi = 0; mi < 4; ++mi)
#pragma unroll
                for (int ni = 0; ni < 4; ++ni)
                    acc[mi][ni] = __builtin_amdgcn_mfma_f32_16x16x32_bf16(
                        a[mi], b[ni], acc[mi][ni], 0, 0, 0);
        }
        __syncthreads();
    }

    const float scale = *wscale;
    const int orow0 = bm * 128 + wr * 64 + ((lane >> 4) << 2);
    const int ocol0 = bn * 128 + wc * 64 + (lane & 15);
#pragma unroll
    for (int ni = 0; ni < 4; ++ni) {
        const int col = ocol0 + 16 * ni;
        const float bb = bias[col];
#pragma unroll
        for (int mi = 0; mi < 4; ++mi) {
            const int row0 = orow0 + 16 * mi;
#pragma unroll
            for (int i = 0; i < 4; ++i)
                out[(size_t)(row0 + i) * N + col] = acc[mi][ni][i] * scale + bb;
        }
    }
}

extern "C" void kernel_launch(void* const* d_in, const int* in_sizes, int n_in,
                              void* d_out, int out_size, void* d_ws, size_t ws_size,
                              hipStream_t stream) {
    const float* x      = (const float*)d_in[0];
    const int*   w      = (const int*)d_in[1];      // int inputs arrive as int32
    const float* wscale = (const float*)d_in[2];
    const float* bias   = (const float*)d_in[3];
    float*       out    = (float*)d_out;

    const int DOUT = in_sizes[3];
    const int DIN  = in_sizes[1] / DOUT;
    const int M    = in_sizes[0] / DIN;

    const size_t xb_bytes = (size_t)M * DIN * 2;
    const size_t wb_bytes = (size_t)DOUT * DIN * 2;

    if (ws_size >= xb_bytes + wb_bytes && (M % 256) == 0 && (DOUT % 256) == 0) {
        unsigned short* xb = (unsigned short*)d_ws;
        unsigned short* wb = (unsigned short*)((char*)d_ws + xb_bytes);

        const long long nx8 = (long long)M * DIN / 8;
        const long long nw8 = (long long)DOUT * DIN / 8;
        convert_x_kernel<<<2048, 256, 0, stream>>>(x, xb, nx8);
        convert_w_kernel<<<2048, 256, 0, stream>>>(w, wb, nw8);

        dim3 grid((M / 256) * (DOUT / 256));
        gemm256_kernel<<<grid, 512, 0, stream>>>(xb, wb, wscale, bias, out, M, DOUT, DIN);
    } else {
        dim3 grid((M / 128) * (DOUT / 128));
        qlinear_fused_kernel<<<grid, 256, 0, stream>>>(x, w, wscale, bias, out, M, DOUT, DIN);
    }
}

// Round 5
// 292.685 us; speedup vs baseline: 1.7496x; 1.0820x over previous
//
#include <hip/hip_runtime.h>
#include <hip/hip_bf16.h>

typedef __attribute__((ext_vector_type(8))) short bf16x8;
typedef __attribute__((ext_vector_type(4))) float f32x4;
typedef __attribute__((ext_vector_type(4))) int i32x4;
typedef __attribute__((ext_vector_type(2))) unsigned int u32x2;
typedef __attribute__((ext_vector_type(4))) unsigned int u32x4;

// RNE fp32 -> bf16 bits (inputs finite; no NaN handling needed)
__device__ __forceinline__ unsigned int f2bf(float f) {
    union { float f; unsigned int u; } v; v.f = f;
    unsigned int u = v.u;
    u += 0x7FFFu + ((u >> 16) & 1u);
    return u >> 16;
}

__device__ __forceinline__ void gl_lds16(const void* gptr, void* lptr) {
    __builtin_amdgcn_global_load_lds(
        (const __attribute__((address_space(1))) unsigned int*)gptr,
        (__attribute__((address_space(3))) unsigned int*)lptr, 16, 0, 0);
}

// ---------- pre-pass converts ----------
__global__ __launch_bounds__(256) void convert_x_kernel(
    const float* __restrict__ x, unsigned short* __restrict__ xb, long long n8)
{
    long long i = (long long)blockIdx.x * blockDim.x + threadIdx.x;
    const long long stride = (long long)gridDim.x * blockDim.x;
    for (; i < n8; i += stride) {
        const f32x4* p = (const f32x4*)(x + i * 8);
        f32x4 v0 = p[0], v1 = p[1];
        u32x4 q;
        q[0] = f2bf(v0[0]) | (f2bf(v0[1]) << 16);
        q[1] = f2bf(v0[2]) | (f2bf(v0[3]) << 16);
        q[2] = f2bf(v1[0]) | (f2bf(v1[1]) << 16);
        q[3] = f2bf(v1[2]) | (f2bf(v1[3]) << 16);
        *(u32x4*)(xb + i * 8) = q;
    }
}

__global__ __launch_bounds__(256) void convert_w_kernel(
    const int* __restrict__ w, unsigned short* __restrict__ wb, long long n8)
{
    long long i = (long long)blockIdx.x * blockDim.x + threadIdx.x;
    const long long stride = (long long)gridDim.x * blockDim.x;
    for (; i < n8; i += stride) {
        const i32x4* p = (const i32x4*)(w + i * 8);
        i32x4 v0 = p[0], v1 = p[1];
        u32x4 q;   // int8 values are exact in bf16
        q[0] = f2bf((float)v0[0]) | (f2bf((float)v0[1]) << 16);
        q[1] = f2bf((float)v0[2]) | (f2bf((float)v0[3]) << 16);
        q[2] = f2bf((float)v1[0]) | (f2bf((float)v1[1]) << 16);
        q[3] = f2bf((float)v1[2]) | (f2bf((float)v1[3]) << 16);
        *(u32x4*)(wb + i * 8) = q;
    }
}

// ---------- 256x256 counted-vmcnt GEMM (T1+T2+T3+T4+T5) ----------
// 512 thr = 8 waves in 4Mx2N; per-wave out 64x128. BK=64.
// LDS: [2 buf][A0|A1|B0|B1] halves of 16KB = 128 KiB.
// Stage rotation per phase: p0->B0(t+1), p1->B1(t+1), p2->A0(t+2), p3->A1(t+2).
// vmcnt(4) once per K-tile (2 newest half-tiles in flight), drained at tail.
__global__ __launch_bounds__(512, 2) void gemm256_kernel(
    const unsigned short* __restrict__ A, const unsigned short* __restrict__ Bw,
    const float* __restrict__ wscale, const float* __restrict__ bias,
    float* __restrict__ out, int M, int N, int K)
{
    __shared__ unsigned char lds[131072];

    const int tid  = threadIdx.x;
    const int lane = tid & 63;
    const int wid  = tid >> 6;
    const int wr   = wid >> 1;   // 0..3 -> 64 output rows each
    const int wc   = wid & 1;    // 0..1 -> 128 output cols each

    const int ntn = N >> 8;
    const int nwg = gridDim.x;
    int bid = blockIdx.x;
    if ((nwg & 7) == 0) {                       // XCD-aware swizzle (T1)
        const int cpx = nwg >> 3;
        bid = (bid & 7) * cpx + (bid >> 3);
    }
    const int bm = bid / ntn;
    const int bn = bid % ntn;
    const int NT = K >> 6;

    const char* Abase = (const char*)(A  + (size_t)bm * 256 * K);
    const char* Bbase = (const char*)(Bw + (size_t)bn * 256 * K);
    const size_t rowb = (size_t)K * 2;

    // staging: half-tile = 128 rows x 128B (16KB); 2 gl_lds per wave.
    // Linear LDS dest; source column pre-swizzled (rule 21): LDS row r holds
    // global col b ^ ((r&7)<<4), with r&7 == lane>>3.
    const int s_colb = (((lane & 7) ^ (lane >> 3)) << 4);
    const int s_rsub = wid * 8 + (lane >> 3);    // 0..63 per q-block
    const int s_ldso = wid * 1024 + lane * 16;

    auto stageHalf = [&](const char* gRowBase, char* lhalf) {
#pragma unroll
        for (int q = 0; q < 2; ++q)
            gl_lds16(gRowBase + (size_t)(q * 64 + s_rsub) * rowb + s_colb,
                     lhalf + q * 8192 + s_ldso);
    };
    // global row-base helpers: tile kt, half h
    auto Ag = [&](int kt, int h) { return Abase + (size_t)kt * 128 + (size_t)(h * 128) * rowb; };
    auto Bg = [&](int kt, int h) { return Bbase + (size_t)kt * 128 + (size_t)(h * 128) * rowb; };

    // fragment-read addressing (swizzled)
    const int arow = (wr * 64  + (lane & 15)) * 128;   // byte row base in A region
    const int brow = (wc * 128 + (lane & 15)) * 128;   // byte row base in B region
    const int csw0 = (((lane >> 4) * 16))      ^ ((lane & 7) << 4);
    const int csw1 = (((lane >> 4) * 16) + 64) ^ ((lane & 7) << 4);

    f32x4 acc[4][8];
#pragma unroll
    for (int mi = 0; mi < 4; ++mi)
#pragma unroll
        for (int ni = 0; ni < 8; ++ni)
            acc[mi][ni] = (f32x4){0.f, 0.f, 0.f, 0.f};

    // ---- prologue: stage tile0 (4 halves) + tile1 A-halves; wait all but newest 2 ----
    stageHalf(Ag(0, 0), (char*)lds + 0);
    stageHalf(Ag(0, 1), (char*)lds + 16384);
    stageHalf(Bg(0, 0), (char*)lds + 32768);
    stageHalf(Bg(0, 1), (char*)lds + 49152);
    if (NT > 1) {
        stageHalf(Ag(1, 0), (char*)lds + 65536);
        stageHalf(Ag(1, 1), (char*)lds + 65536 + 16384);
        asm volatile("s_waitcnt vmcnt(4)" ::: "memory");
    } else {
        asm volatile("s_waitcnt vmcnt(0)" ::: "memory");
    }
    __builtin_amdgcn_sched_barrier(0);
    asm volatile("s_barrier" ::: "memory");

#pragma unroll 2
    for (int kt = 0; kt < NT; ++kt) {
        const int c = kt & 1;
        const char* Al = (const char*)lds + (c << 16);
        const char* Bl = Al + 32768;
        char* nbuf = (char*)lds + ((c ^ 1) << 16);   // buffer of tile kt+1
        char* cbuf = (char*)lds + (c << 16);         // buffer of tile kt+2
        bf16x8 a0[4], a1[4], b[4], b2[4];

        // ---- p0: read A kk0 + B fn0-3 kk0; stage B0(kt+1) ----
#pragma unroll
        for (int fm = 0; fm < 4; ++fm) a0[fm] = *(const bf16x8*)(Al + arow + fm * 16 * 128 + csw0);
#pragma unroll
        for (int fn = 0; fn < 4; ++fn) b[fn]  = *(const bf16x8*)(Bl + brow + fn * 16 * 128 + csw0);
        if (kt + 1 < NT) stageHalf(Bg(kt + 1, 0), nbuf + 32768);
        asm volatile("s_barrier" ::: "memory");
        __builtin_amdgcn_s_setprio(1);
#pragma unroll
        for (int fm = 0; fm < 4; ++fm)
#pragma unroll
            for (int fn = 0; fn < 4; ++fn)
                acc[fm][fn] = __builtin_amdgcn_mfma_f32_16x16x32_bf16(a0[fm], b[fn], acc[fm][fn], 0, 0, 0);
        __builtin_amdgcn_s_setprio(0);
        asm volatile("s_barrier" ::: "memory");

        // ---- p1: read A kk1 + B fn4-7 kk0; stage B1(kt+1) ----
#pragma unroll
        for (int fm = 0; fm < 4; ++fm) a1[fm] = *(const bf16x8*)(Al + arow + fm * 16 * 128 + csw1);
#pragma unroll
        for (int fn = 0; fn < 4; ++fn) b2[fn] = *(const bf16x8*)(Bl + brow + (fn + 4) * 16 * 128 + csw0);
        if (kt + 1 < NT) stageHalf(Bg(kt + 1, 1), nbuf + 49152);
        asm volatile("s_barrier" ::: "memory");
        __builtin_amdgcn_s_setprio(1);
#pragma unroll
        for (int fm = 0; fm < 4; ++fm)
#pragma unroll
            for (int fn = 0; fn < 4; ++fn)
                acc[fm][fn + 4] = __builtin_amdgcn_mfma_f32_16x16x32_bf16(a0[fm], b2[fn], acc[fm][fn + 4], 0, 0, 0);
        __builtin_amdgcn_s_setprio(0);
        // A-region reads (a1) must complete before p2 stages into A0 region:
        asm volatile("s_waitcnt lgkmcnt(0)" ::: "memory");
        asm volatile("s_barrier" ::: "memory");

        // ---- p2: read B fn0-7 kk1; stage A0(kt+2) ----
#pragma unroll
        for (int fn = 0; fn < 4; ++fn) b[fn]  = *(const bf16x8*)(Bl + brow + fn * 16 * 128 + csw1);
#pragma unroll
        for (int fn = 0; fn < 4; ++fn) b2[fn] = *(const bf16x8*)(Bl + brow + (fn + 4) * 16 * 128 + csw1);
        if (kt + 2 < NT) stageHalf(Ag(kt + 2, 0), cbuf);
        asm volatile("s_barrier" ::: "memory");
        __builtin_amdgcn_s_setprio(1);
#pragma unroll
        for (int fm = 0; fm < 4; ++fm)
#pragma unroll
            for (int fn = 0; fn < 4; ++fn)
                acc[fm][fn] = __builtin_amdgcn_mfma_f32_16x16x32_bf16(a1[fm], b[fn], acc[fm][fn], 0, 0, 0);
        __builtin_amdgcn_s_setprio(0);
        asm volatile("s_barrier" ::: "memory");

        // ---- p3: stage A1(kt+2); MFMA a1 x b2; counted vmcnt ----
        if (kt + 2 < NT) stageHalf(Ag(kt + 2, 1), cbuf + 16384);
        asm volatile("s_barrier" ::: "memory");
        __builtin_amdgcn_s_setprio(1);
#pragma unroll
        for (int fm = 0; fm < 4; ++fm)
#pragma unroll
            for (int fn = 0; fn < 4; ++fn)
                acc[fm][fn + 4] = __builtin_amdgcn_mfma_f32_16x16x32_bf16(a1[fm], b2[fn], acc[fm][fn + 4], 0, 0, 0);
        __builtin_amdgcn_s_setprio(0);
        if (kt + 2 < NT) { asm volatile("s_waitcnt vmcnt(4)" ::: "memory"); }
        else             { asm volatile("s_waitcnt vmcnt(0)" ::: "memory"); }
        __builtin_amdgcn_sched_barrier(0);
        asm volatile("s_barrier" ::: "memory");
    }

    // epilogue: out = acc*scale + bias ; C/D layout col=lane&15, row=(lane>>4)*4+i
    const float scale = *wscale;
    const int orow0 = bm * 256 + wr * 64  + ((lane >> 4) << 2);
    const int ocol0 = bn * 256 + wc * 128 + (lane & 15);
#pragma unroll
    for (int fn = 0; fn < 8; ++fn) {
        const int col = ocol0 + 16 * fn;
        const float bb = bias[col];
#pragma unroll
        for (int fm = 0; fm < 4; ++fm) {
            const int row0 = orow0 + 16 * fm;
#pragma unroll
            for (int i = 0; i < 4; ++i)
                out[(size_t)(row0 + i) * N + col] = acc[fm][fn][i] * scale + bb;
        }
    }
}

// ---------- fallback: round-2 fused kernel (passes; used only if ws too small) ----------
__device__ __forceinline__ int swz(int row, int byte_in_row) {
    return row * 128 + (byte_in_row ^ ((row & 7) << 4));
}

__global__ __launch_bounds__(256) void qlinear_fused_kernel(
    const float* __restrict__ X, const int* __restrict__ W,
    const float* __restrict__ wscale, const float* __restrict__ bias,
    float* __restrict__ out, int M, int N, int K)
{
    __shared__ unsigned char smem[32768];

    const int t    = threadIdx.x;
    const int lane = t & 63;
    const int wid  = t >> 6;
    const int wr   = wid >> 1;
    const int wc   = wid & 1;

    const int ntn = N >> 7;
    const int bm  = blockIdx.x / ntn;
    const int bn  = blockIdx.x % ntn;
    const int NT  = K >> 6;

    const float* Ab = X + (size_t)bm * 128 * K;
    const int*   Bb = W + (size_t)bn * 128 * K;

    const int srow = t >> 4, sc4 = t & 15;

    f32x4 av[8];
    i32x4 bv[8];

    auto loadAB = [&](int kt) {
        const float* Ap = Ab + kt * 64 + sc4 * 4;
#pragma unroll
        for (int l = 0; l < 8; ++l)
            av[l] = *(const f32x4*)(Ap + (size_t)(srow + 16 * l) * K);
        const int* Bp = Bb + kt * 64 + sc4 * 4;
#pragma unroll
        for (int l = 0; l < 8; ++l)
            bv[l] = *(const i32x4*)(Bp + (size_t)(srow + 16 * l) * K);
    };

    auto writeAB = [&]() {
#pragma unroll
        for (int l = 0; l < 8; ++l) {
            const int row = srow + 16 * l;
            u32x2 pk;
            pk[0] = f2bf(av[l][0]) | (f2bf(av[l][1]) << 16);
            pk[1] = f2bf(av[l][2]) | (f2bf(av[l][3]) << 16);
            *(u32x2*)(smem + swz(row, sc4 * 8)) = pk;
        }
#pragma unroll
        for (int l = 0; l < 8; ++l) {
            const int row = srow + 16 * l;
            u32x2 pk;
            pk[0] = f2bf((float)bv[l][0]) | (f2bf((float)bv[l][1]) << 16);
            pk[1] = f2bf((float)bv[l][2]) | (f2bf((float)bv[l][3]) << 16);
            *(u32x2*)(smem + 16384 + swz(row, sc4 * 8)) = pk;
        }
    };

    f32x4 acc[4][4];
#pragma unroll
    for (int mi = 0; mi < 4; ++mi)
#pragma unroll
        for (int ni = 0; ni < 4; ++ni)
            acc[mi][ni] = (f32x4){0.f, 0.f, 0.f, 0.f};

    const int kbyte = (lane >> 4) * 16;
    const int afr   = wr * 64 + (lane & 15);
    const int bfr   = wc * 64 + (lane & 15);

    loadAB(0);

    for (int kt = 0; kt < NT; ++kt) {
        writeAB();
        __syncthreads();
        if (kt + 1 < NT) loadAB(kt + 1);
#pragma unroll
        for (int kk = 0; kk < 2; ++kk) {
            bf16x8 a[4], b[4];
#pragma unroll
            for (int mi = 0; mi < 4; ++mi)
                a[mi] = *(const bf16x8*)(smem + swz(afr + 16 * mi, kk * 64 + kbyte));
#pragma unroll
            for (int ni = 0; ni < 4; ++ni)
                b[ni] = *(const bf16x8*)(smem + 16384 + swz(bfr + 16 * ni, kk * 64 + kbyte));
#pragma unroll
            for (int mi = 0; mi < 4; ++mi)
#pragma unroll
                for (int ni = 0; ni < 4; ++ni)
                    acc[mi][ni] = __builtin_amdgcn_mfma_f32_16x16x32_bf16(
                        a[mi], b[ni], acc[mi][ni], 0, 0, 0);
        }
        __syncthreads();
    }

    const float scale = *wscale;
    const int orow0 = bm * 128 + wr * 64 + ((lane >> 4) << 2);
    const int ocol0 = bn * 128 + wc * 64 + (lane & 15);
#pragma unroll
    for (int ni = 0; ni < 4; ++ni) {
        const int col = ocol0 + 16 * ni;
        const float bb = bias[col];
#pragma unroll
        for (int mi = 0; mi < 4; ++mi) {
            const int row0 = orow0 + 16 * mi;
#pragma unroll
            for (int i = 0; i < 4; ++i)
                out[(size_t)(row0 + i) * N + col] = acc[mi][ni][i] * scale + bb;
        }
    }
}

extern "C" void kernel_launch(void* const* d_in, const int* in_sizes, int n_in,
                              void* d_out, int out_size, void* d_ws, size_t ws_size,
                              hipStream_t stream) {
    const float* x      = (const float*)d_in[0];
    const int*   w      = (const int*)d_in[1];      // int inputs arrive as int32
    const float* wscale = (const float*)d_in[2];
    const float* bias   = (const float*)d_in[3];
    float*       out    = (float*)d_out;

    const int DOUT = in_sizes[3];
    const int DIN  = in_sizes[1] / DOUT;
    const int M    = in_sizes[0] / DIN;

    const size_t xb_bytes = (size_t)M * DIN * 2;
    const size_t wb_bytes = (size_t)DOUT * DIN * 2;

    if (ws_size >= xb_bytes + wb_bytes && (M % 256) == 0 && (DOUT % 256) == 0) {
        unsigned short* xb = (unsigned short*)d_ws;
        unsigned short* wb = (unsigned short*)((char*)d_ws + xb_bytes);

        const long long nx8 = (long long)M * DIN / 8;
        const long long nw8 = (long long)DOUT * DIN / 8;
        convert_x_kernel<<<2048, 256, 0, stream>>>(x, xb, nx8);
        convert_w_kernel<<<2048, 256, 0, stream>>>(w, wb, nw8);

        dim3 grid((M / 256) * (DOUT / 256));
        gemm256_kernel<<<grid, 512, 0, stream>>>(xb, wb, wscale, bias, out, M, DOUT, DIN);
    } else {
        dim3 grid((M / 128) * (DOUT / 128));
        qlinear_fused_kernel<<<grid, 256, 0, stream>>>(x, w, wscale, bias, out, M, DOUT, DIN);
    }
}

// Round 7
// 285.829 us; speedup vs baseline: 1.7916x; 1.0240x over previous
//
#include <hip/hip_runtime.h>
#include <hip/hip_bf16.h>

typedef __attribute__((ext_vector_type(8))) short bf16x8;
typedef __attribute__((ext_vector_type(4))) float f32x4;
typedef __attribute__((ext_vector_type(4))) int i32x4;
typedef __attribute__((ext_vector_type(2))) unsigned int u32x2;
typedef __attribute__((ext_vector_type(4))) unsigned int u32x4;

// RNE fp32 -> bf16 bits (inputs finite; no NaN handling needed)
__device__ __forceinline__ unsigned int f2bf(float f) {
    union { float f; unsigned int u; } v; v.f = f;
    unsigned int u = v.u;
    u += 0x7FFFu + ((u >> 16) & 1u);
    return u >> 16;
}

__device__ __forceinline__ void gl_lds16(const void* gptr, void* lptr) {
    __builtin_amdgcn_global_load_lds(
        (const __attribute__((address_space(1))) unsigned int*)gptr,
        (__attribute__((address_space(3))) unsigned int*)lptr, 16, 0, 0);
}

// ---------- pre-pass converts ----------
__global__ __launch_bounds__(256) void convert_x_kernel(
    const float* __restrict__ x, unsigned short* __restrict__ xb, long long n8)
{
    long long i = (long long)blockIdx.x * blockDim.x + threadIdx.x;
    const long long stride = (long long)gridDim.x * blockDim.x;
    for (; i < n8; i += stride) {
        const f32x4* p = (const f32x4*)(x + i * 8);
        f32x4 v0 = p[0], v1 = p[1];
        u32x4 q;
        q[0] = f2bf(v0[0]) | (f2bf(v0[1]) << 16);
        q[1] = f2bf(v0[2]) | (f2bf(v0[3]) << 16);
        q[2] = f2bf(v1[0]) | (f2bf(v1[1]) << 16);
        q[3] = f2bf(v1[2]) | (f2bf(v1[3]) << 16);
        *(u32x4*)(xb + i * 8) = q;
    }
}

__global__ __launch_bounds__(256) void convert_w_kernel(
    const int* __restrict__ w, unsigned short* __restrict__ wb, long long n8)
{
    long long i = (long long)blockIdx.x * blockDim.x + threadIdx.x;
    const long long stride = (long long)gridDim.x * blockDim.x;
    for (; i < n8; i += stride) {
        const i32x4* p = (const i32x4*)(w + i * 8);
        i32x4 v0 = p[0], v1 = p[1];
        u32x4 q;   // int8 values are exact in bf16
        q[0] = f2bf((float)v0[0]) | (f2bf((float)v0[1]) << 16);
        q[1] = f2bf((float)v0[2]) | (f2bf((float)v0[3]) << 16);
        q[2] = f2bf((float)v1[0]) | (f2bf((float)v1[1]) << 16);
        q[3] = f2bf((float)v1[2]) | (f2bf((float)v1[3]) << 16);
        *(u32x4*)(wb + i * 8) = q;
    }
}

// ---------- 256x256 pipelined GEMM (T1+T2+T3+T4+T5, reads 1 phase ahead) ----------
// 512 thr = 8 waves in 4Mx2N; per-wave out 64x128. BK=64.
// LDS: [2 buf][A0|A1|B0|B1] 16KB halves = 128 KiB.
// Phase p issues phase p+1's ds_reads, MFMAs on regs read last phase.
// 3 barriers/tile:
//   MID (end p1, lgkmcnt(0) first): all A(t)-reads AND prev-tile prefetch reads
//       landed -> safe to DMA A(t+2) into this buffer's A region at p2.
//   B3  (p3, after counted vmcnt): globalizes vmcnt across waves -> entire
//       nb (tile t+1) is DMA-complete before ANY wave prefetch-reads it.
//       (r6's race: vmcnt is per-wave; half-tiles are written by all waves.)
//   END (end p3): all B(t)-reads landed -> next tile's p0 may DMA B(t+2) here.
// Stage rotation: p0->B0(t+1), p1->B1(t+1), p2->A0(t+2), p3->A1(t+2).
__global__ __launch_bounds__(512, 2) void gemm256_kernel(
    const unsigned short* __restrict__ A, const unsigned short* __restrict__ Bw,
    const float* __restrict__ wscale, const float* __restrict__ bias,
    float* __restrict__ out, int M, int N, int K)
{
    __shared__ unsigned char lds[131072];

    const int tid  = threadIdx.x;
    const int lane = tid & 63;
    const int wid  = tid >> 6;
    const int wr   = wid >> 1;   // 0..3 -> 64 output rows each
    const int wc   = wid & 1;    // 0..1 -> 128 output cols each

    const int ntn = N >> 8;
    const int nwg = gridDim.x;
    int bid = blockIdx.x;
    if ((nwg & 7) == 0) {                       // XCD-aware swizzle (T1)
        const int cpx = nwg >> 3;
        bid = (bid & 7) * cpx + (bid >> 3);
    }
    const int bm = bid / ntn;
    const int bn = bid % ntn;
    const int NT = K >> 6;

    const char* Abase = (const char*)(A  + (size_t)bm * 256 * K);
    const char* Bbase = (const char*)(Bw + (size_t)bn * 256 * K);
    const size_t rowb = (size_t)K * 2;

    // staging: half-tile = 128 rows x 128B (16KB); 2 gl_lds per thread.
    // Linear LDS dest; source column pre-swizzled (rule 21).
    const int s_colb = (((lane & 7) ^ (lane >> 3)) << 4);
    const int s_rsub = wid * 8 + (lane >> 3);
    const int s_ldso = wid * 1024 + lane * 16;

    auto stageHalf = [&](const char* gRowBase, char* lhalf) {
#pragma unroll
        for (int q = 0; q < 2; ++q)
            gl_lds16(gRowBase + (size_t)(q * 64 + s_rsub) * rowb + s_colb,
                     lhalf + q * 8192 + s_ldso);
    };
    auto Ag = [&](int kt, int h) { return Abase + (size_t)kt * 128 + (size_t)(h * 128) * rowb; };
    auto Bg = [&](int kt, int h) { return Bbase + (size_t)kt * 128 + (size_t)(h * 128) * rowb; };

    // fragment-read addressing (swizzled)
    const int arow = (wr * 64  + (lane & 15)) * 128;
    const int brow = (wc * 128 + (lane & 15)) * 128;
    const int csw0 = (((lane >> 4) * 16))      ^ ((lane & 7) << 4);
    const int csw1 = (((lane >> 4) * 16) + 64) ^ ((lane & 7) << 4);

    f32x4 acc[4][8];
#pragma unroll
    for (int mi = 0; mi < 4; ++mi)
#pragma unroll
        for (int ni = 0; ni < 8; ++ni)
            acc[mi][ni] = (f32x4){0.f, 0.f, 0.f, 0.f};

    bf16x8 a0[4], a1[4], bA[4], bB[4];

    // ---- prologue ----
    stageHalf(Ag(0, 0), (char*)lds + 0);
    stageHalf(Ag(0, 1), (char*)lds + 16384);
    stageHalf(Bg(0, 0), (char*)lds + 32768);
    stageHalf(Bg(0, 1), (char*)lds + 49152);
    if (NT > 1) {
        stageHalf(Ag(1, 0), (char*)lds + 65536);
        stageHalf(Ag(1, 1), (char*)lds + 65536 + 16384);
        asm volatile("s_waitcnt vmcnt(4)" ::: "memory");
    } else {
        asm volatile("s_waitcnt vmcnt(0)" ::: "memory");
    }
    __builtin_amdgcn_sched_barrier(0);
    asm volatile("s_barrier" ::: "memory");
    // R0 of tile 0: a0 (kk0) + bA (fn0-3, kk0)
    {
        const char* Al = (const char*)lds;
        const char* Bl = Al + 32768;
#pragma unroll
        for (int fm = 0; fm < 4; ++fm) a0[fm] = *(const bf16x8*)(Al + arow + fm * 2048 + csw0);
#pragma unroll
        for (int fn = 0; fn < 4; ++fn) bA[fn] = *(const bf16x8*)(Bl + brow + fn * 2048 + csw0);
    }

#pragma unroll 2
    for (int kt = 0; kt < NT; ++kt) {
        const int c = kt & 1;
        const char* Al = (const char*)lds + (c << 16);
        const char* Bl = Al + 32768;
        char* nb = (char*)lds + ((c ^ 1) << 16);   // buffer of tile kt+1
        char* cb = (char*)lds + (c << 16);         // buffer of tile kt+2

        // ---- p0: stage B0(t+1); read R1 {a1 kk1, bB fn4-7 kk0}; MFMA a0 x bA ----
        if (kt + 1 < NT) stageHalf(Bg(kt + 1, 0), nb + 32768);
#pragma unroll
        for (int fm = 0; fm < 4; ++fm) a1[fm] = *(const bf16x8*)(Al + arow + fm * 2048 + csw1);
#pragma unroll
        for (int fn = 0; fn < 4; ++fn) bB[fn] = *(const bf16x8*)(Bl + brow + (fn + 4) * 2048 + csw0);
        __builtin_amdgcn_s_setprio(1);
#pragma unroll
        for (int fm = 0; fm < 4; ++fm)
#pragma unroll
            for (int fn = 0; fn < 4; ++fn)
                acc[fm][fn] = __builtin_amdgcn_mfma_f32_16x16x32_bf16(a0[fm], bA[fn], acc[fm][fn], 0, 0, 0);
        __builtin_amdgcn_s_setprio(0);

        // ---- p1: stage B1(t+1); read R2 {bA <- fn0-3 kk1}; MFMA a0 x bB; MID ----
        if (kt + 1 < NT) stageHalf(Bg(kt + 1, 1), nb + 49152);
#pragma unroll
        for (int fn = 0; fn < 4; ++fn) bA[fn] = *(const bf16x8*)(Bl + brow + fn * 2048 + csw1);
        __builtin_amdgcn_s_setprio(1);
#pragma unroll
        for (int fm = 0; fm < 4; ++fm)
#pragma unroll
            for (int fn = 0; fn < 4; ++fn)
                acc[fm][fn + 4] = __builtin_amdgcn_mfma_f32_16x16x32_bf16(a0[fm], bB[fn], acc[fm][fn + 4], 0, 0, 0);
        __builtin_amdgcn_s_setprio(0);
        asm volatile("s_waitcnt lgkmcnt(0)" ::: "memory");   // all A(t)-reads + old prefetch landed
        asm volatile("s_barrier" ::: "memory");              // MID: A-region handoff

        // ---- p2: stage A0(t+2); read R3 {bB <- fn4-7 kk1}; MFMA a1 x bA ----
        if (kt + 2 < NT) stageHalf(Ag(kt + 2, 0), cb + 0);
#pragma unroll
        for (int fn = 0; fn < 4; ++fn) bB[fn] = *(const bf16x8*)(Bl + brow + (fn + 4) * 2048 + csw1);
        __builtin_amdgcn_s_setprio(1);
#pragma unroll
        for (int fm = 0; fm < 4; ++fm)
#pragma unroll
            for (int fn = 0; fn < 4; ++fn)
                acc[fm][fn] = __builtin_amdgcn_mfma_f32_16x16x32_bf16(a1[fm], bA[fn], acc[fm][fn], 0, 0, 0);
        __builtin_amdgcn_s_setprio(0);

        // ---- p3: stage A1(t+2); vmcnt; B3 barrier; read R0'(t+1); MFMA a1 x bB; END ----
        if (kt + 2 < NT) stageHalf(Ag(kt + 2, 1), cb + 16384);
        if (kt + 1 < NT) {
            if (kt + 2 < NT) { asm volatile("s_waitcnt vmcnt(4)" ::: "memory"); }
            else             { asm volatile("s_waitcnt vmcnt(0)" ::: "memory"); }
            __builtin_amdgcn_sched_barrier(0);
            asm volatile("s_barrier" ::: "memory");          // B3: globalize vmcnt ->
                                                             // all waves' t+1 stages landed
            const char* nAl = (const char*)nb;
            const char* nBl = (const char*)nb + 32768;
#pragma unroll
            for (int fm = 0; fm < 4; ++fm) a0[fm] = *(const bf16x8*)(nAl + arow + fm * 2048 + csw0);
#pragma unroll
            for (int fn = 0; fn < 4; ++fn) bA[fn] = *(const bf16x8*)(nBl + brow + fn * 2048 + csw0);
        }
        __builtin_amdgcn_s_setprio(1);
#pragma unroll
        for (int fm = 0; fm < 4; ++fm)
#pragma unroll
            for (int fn = 0; fn < 4; ++fn)
                acc[fm][fn + 4] = __builtin_amdgcn_mfma_f32_16x16x32_bf16(a1[fm], bB[fn], acc[fm][fn + 4], 0, 0, 0);
        __builtin_amdgcn_s_setprio(0);
        asm volatile("s_barrier" ::: "memory");              // END: B-region handoff + swap
    }

    // epilogue: out = acc*scale + bias ; C/D layout col=lane&15, row=(lane>>4)*4+i
    const float scale = *wscale;
    const int orow0 = bm * 256 + wr * 64  + ((lane >> 4) << 2);
    const int ocol0 = bn * 256 + wc * 128 + (lane & 15);
#pragma unroll
    for (int fn = 0; fn < 8; ++fn) {
        const int col = ocol0 + 16 * fn;
        const float bb = bias[col];
#pragma unroll
        for (int fm = 0; fm < 4; ++fm) {
            const int row0 = orow0 + 16 * fm;
#pragma unroll
            for (int i = 0; i < 4; ++i)
                out[(size_t)(row0 + i) * N + col] = acc[fm][fn][i] * scale + bb;
        }
    }
}

// ---------- fallback: round-2 fused kernel (passes; used only if ws too small) ----------
__device__ __forceinline__ int swz(int row, int byte_in_row) {
    return row * 128 + (byte_in_row ^ ((row & 7) << 4));
}

__global__ __launch_bounds__(256) void qlinear_fused_kernel(
    const float* __restrict__ X, const int* __restrict__ W,
    const float* __restrict__ wscale, const float* __restrict__ bias,
    float* __restrict__ out, int M, int N, int K)
{
    __shared__ unsigned char smem[32768];

    const int t    = threadIdx.x;
    const int lane = t & 63;
    const int wid  = t >> 6;
    const int wr   = wid >> 1;
    const int wc   = wid & 1;

    const int ntn = N >> 7;
    const int bm  = blockIdx.x / ntn;
    const int bn  = blockIdx.x % ntn;
    const int NT  = K >> 6;

    const float* Ab = X + (size_t)bm * 128 * K;
    const int*   Bb = W + (size_t)bn * 128 * K;

    const int srow = t >> 4, sc4 = t & 15;

    f32x4 av[8];
    i32x4 bv[8];

    auto loadAB = [&](int kt) {
        const float* Ap = Ab + kt * 64 + sc4 * 4;
#pragma unroll
        for (int l = 0; l < 8; ++l)
            av[l] = *(const f32x4*)(Ap + (size_t)(srow + 16 * l) * K);
        const int* Bp = Bb + kt * 64 + sc4 * 4;
#pragma unroll
        for (int l = 0; l < 8; ++l)
            bv[l] = *(const i32x4*)(Bp + (size_t)(srow + 16 * l) * K);
    };

    auto writeAB = [&]() {
#pragma unroll
        for (int l = 0; l < 8; ++l) {
            const int row = srow + 16 * l;
            u32x2 pk;
            pk[0] = f2bf(av[l][0]) | (f2bf(av[l][1]) << 16);
            pk[1] = f2bf(av[l][2]) | (f2bf(av[l][3]) << 16);
            *(u32x2*)(smem + swz(row, sc4 * 8)) = pk;
        }
#pragma unroll
        for (int l = 0; l < 8; ++l) {
            const int row = srow + 16 * l;
            u32x2 pk;
            pk[0] = f2bf((float)bv[l][0]) | (f2bf((float)bv[l][1]) << 16);
            pk[1] = f2bf((float)bv[l][2]) | (f2bf((float)bv[l][3]) << 16);
            *(u32x2*)(smem + 16384 + swz(row, sc4 * 8)) = pk;
        }
    };

    f32x4 acc[4][4];
#pragma unroll
    for (int mi = 0; mi < 4; ++mi)
#pragma unroll
        for (int ni = 0; ni < 4; ++ni)
            acc[mi][ni] = (f32x4){0.f, 0.f, 0.f, 0.f};

    const int kbyte = (lane >> 4) * 16;
    const int afr   = wr * 64 + (lane & 15);
    const int bfr   = wc * 64 + (lane & 15);

    loadAB(0);

    for (int kt = 0; kt < NT; ++kt) {
        writeAB();
        __syncthreads();
        if (kt + 1 < NT) loadAB(kt + 1);
#pragma unroll
        for (int kk = 0; kk < 2; ++kk) {
            bf16x8 a[4], b[4];
#pragma unroll
            for (int mi = 0; mi < 4; ++mi)
                a[mi] = *(const bf16x8*)(smem + swz(afr + 16 * mi, kk * 64 + kbyte));
#pragma unroll
            for (int ni = 0; ni < 4; ++ni)
                b[ni] = *(const bf16x8*)(smem + 16384 + swz(bfr + 16 * ni, kk * 64 + kbyte));
#pragma unroll
            for (int mi = 0; mi < 4; ++mi)
#pragma unroll
                for (int ni = 0; ni < 4; ++ni)
                    acc[mi][ni] = __builtin_amdgcn_mfma_f32_16x16x32_bf16(
                        a[mi], b[ni], acc[mi][ni], 0, 0, 0);
        }
        __syncthreads();
    }

    const float scale = *wscale;
    const int orow0 = bm * 128 + wr * 64 + ((lane >> 4) << 2);
    const int ocol0 = bn * 128 + wc * 64 + (lane & 15);
#pragma unroll
    for (int ni = 0; ni < 4; ++ni) {
        const int col = ocol0 + 16 * ni;
        const float bb = bias[col];
#pragma unroll
        for (int mi = 0; mi < 4; ++mi) {
            const int row0 = orow0 + 16 * mi;
#pragma unroll
            for (int i = 0; i < 4; ++i)
                out[(size_t)(row0 + i) * N + col] = acc[mi][ni][i] * scale + bb;
        }
    }
}

extern "C" void kernel_launch(void* const* d_in, const int* in_sizes, int n_in,
                              void* d_out, int out_size, void* d_ws, size_t ws_size,
                              hipStream_t stream) {
    const float* x      = (const float*)d_in[0];
    const int*   w      = (const int*)d_in[1];      // int inputs arrive as int32
    const float* wscale = (const float*)d_in[2];
    const float* bias   = (const float*)d_in[3];
    float*       out    = (float*)d_out;

    const int DOUT = in_sizes[3];
    const int DIN  = in_sizes[1] / DOUT;
    const int M    = in_sizes[0] / DIN;

    const size_t xb_bytes = (size_t)M * DIN * 2;
    const size_t wb_bytes = (size_t)DOUT * DIN * 2;

    if (ws_size >= xb_bytes + wb_bytes && (M % 256) == 0 && (DOUT % 256) == 0) {
        unsigned short* xb = (unsigned short*)d_ws;
        unsigned short* wb = (unsigned short*)((char*)d_ws + xb_bytes);

        const long long nx8 = (long long)M * DIN / 8;
        const long long nw8 = (long long)DOUT * DIN / 8;
        convert_x_kernel<<<2048, 256, 0, stream>>>(x, xb, nx8);
        convert_w_kernel<<<2048, 256, 0, stream>>>(w, wb, nw8);

        dim3 grid((M / 256) * (DOUT / 256));
        gemm256_kernel<<<grid, 512, 0, stream>>>(xb, wb, wscale, bias, out, M, DOUT, DIN);
    } else {
        dim3 grid((M / 128) * (DOUT / 128));
        qlinear_fused_kernel<<<grid, 256, 0, stream>>>(x, w, wscale, bias, out, M, DOUT, DIN);
    }
}

// Round 8
// 284.887 us; speedup vs baseline: 1.7975x; 1.0033x over previous
//
#include <hip/hip_runtime.h>
#include <hip/hip_bf16.h>

typedef __attribute__((ext_vector_type(8))) short bf16x8;
typedef __attribute__((ext_vector_type(4))) float f32x4;
typedef __attribute__((ext_vector_type(4))) int i32x4;
typedef __attribute__((ext_vector_type(2))) unsigned int u32x2;
typedef __attribute__((ext_vector_type(4))) unsigned int u32x4;

// RNE fp32 -> bf16 bits (inputs finite; no NaN handling needed)
__device__ __forceinline__ unsigned int f2bf(float f) {
    union { float f; unsigned int u; } v; v.f = f;
    unsigned int u = v.u;
    u += 0x7FFFu + ((u >> 16) & 1u);
    return u >> 16;
}

__device__ __forceinline__ void gl_lds16(const void* gptr, void* lptr) {
    __builtin_amdgcn_global_load_lds(
        (const __attribute__((address_space(1))) unsigned int*)gptr,
        (__attribute__((address_space(3))) unsigned int*)lptr, 16, 0, 0);
}

// ---------- pre-pass converts ----------
__global__ __launch_bounds__(256) void convert_x_kernel(
    const float* __restrict__ x, unsigned short* __restrict__ xb, long long n8)
{
    long long i = (long long)blockIdx.x * blockDim.x + threadIdx.x;
    const long long stride = (long long)gridDim.x * blockDim.x;
    for (; i < n8; i += stride) {
        const f32x4* p = (const f32x4*)(x + i * 8);
        f32x4 v0 = p[0], v1 = p[1];
        u32x4 q;
        q[0] = f2bf(v0[0]) | (f2bf(v0[1]) << 16);
        q[1] = f2bf(v0[2]) | (f2bf(v0[3]) << 16);
        q[2] = f2bf(v1[0]) | (f2bf(v1[1]) << 16);
        q[3] = f2bf(v1[2]) | (f2bf(v1[3]) << 16);
        *(u32x4*)(xb + i * 8) = q;
    }
}

__global__ __launch_bounds__(256) void convert_w_kernel(
    const int* __restrict__ w, unsigned short* __restrict__ wb, long long n8)
{
    long long i = (long long)blockIdx.x * blockDim.x + threadIdx.x;
    const long long stride = (long long)gridDim.x * blockDim.x;
    for (; i < n8; i += stride) {
        const i32x4* p = (const i32x4*)(w + i * 8);
        i32x4 v0 = p[0], v1 = p[1];
        u32x4 q;   // int8 values are exact in bf16
        q[0] = f2bf((float)v0[0]) | (f2bf((float)v0[1]) << 16);
        q[1] = f2bf((float)v0[2]) | (f2bf((float)v0[3]) << 16);
        q[2] = f2bf((float)v1[0]) | (f2bf((float)v1[1]) << 16);
        q[3] = f2bf((float)v1[2]) | (f2bf((float)v1[3]) << 16);
        *(u32x4*)(wb + i * 8) = q;
    }
}

// ---------- 256x256 pipelined GEMM, B triple-buffered (T1+T2+T3+T4+T5) ----------
// 512 thr = 8 waves in 4Mx2N; per-wave out 64x128. BK=64.
// LDS 160KB: A dbuf 2x32KB @ {0,32768}; B tribuf 3x32KB @ 65536+{0,1,2}*32768.
// Phase p issues phase p+1's ds_reads; MFMAs run on regs read last phase.
// Stage rotation during tile t: p0->B0(t+2), p1->B1(t+2) [Bbuf[(t+2)%3], which
// held B(t-1), fully read before END(t-1)]; p2->A0(t+2), p3->A1(t+2) [current
// Abuf, A-region freed at MID]. B-lead ~10 phases, A-lead 4-6 phases.
// 3 barriers/tile:
//   MID (end p1, lgkmcnt(0) first): all A(t)-reads (incl. prev prefetch) landed
//       -> safe to DMA A(t+2) over this Abuf at p2.
//   B3  (p3, after vmcnt(8)): globalizes vmcnt -> tile t+1 (staged in t-1) is
//       DMA-complete across ALL waves before any prefetch-read of it.
//   END (end p3): all B(t)-reads landed -> next tile may DMA into B rotation.
// vmcnt(8) = tile t's own 8 stage-loads may remain in flight.
__global__ __launch_bounds__(512, 2) void gemm256_kernel(
    const unsigned short* __restrict__ A, const unsigned short* __restrict__ Bw,
    const float* __restrict__ wscale, const float* __restrict__ bias,
    float* __restrict__ out, int M, int N, int K)
{
    __shared__ unsigned char lds[163840];
    const int B0OFF = 65536;

    const int tid  = threadIdx.x;
    const int lane = tid & 63;
    const int wid  = tid >> 6;
    const int wr   = wid >> 1;   // 0..3 -> 64 output rows each
    const int wc   = wid & 1;    // 0..1 -> 128 output cols each

    const int ntn = N >> 8;
    const int nwg = gridDim.x;
    int bid = blockIdx.x;
    if ((nwg & 7) == 0) {                       // XCD-aware swizzle (T1)
        const int cpx = nwg >> 3;
        bid = (bid & 7) * cpx + (bid >> 3);
    }
    const int bm = bid / ntn;
    const int bn = bid % ntn;
    const int NT = K >> 6;

    const char* Abase = (const char*)(A  + (size_t)bm * 256 * K);
    const char* Bbase = (const char*)(Bw + (size_t)bn * 256 * K);
    const size_t rowb = (size_t)K * 2;

    // staging: half-tile = 128 rows x 128B (16KB); 2 gl_lds per thread.
    // Linear LDS dest; source column pre-swizzled (rule 21).
    const int s_colb = (((lane & 7) ^ (lane >> 3)) << 4);
    const int s_rsub = wid * 8 + (lane >> 3);
    const int s_ldso = wid * 1024 + lane * 16;

    auto stageHalf = [&](const char* gRowBase, char* lhalf) {
#pragma unroll
        for (int q = 0; q < 2; ++q)
            gl_lds16(gRowBase + (size_t)(q * 64 + s_rsub) * rowb + s_colb,
                     lhalf + q * 8192 + s_ldso);
    };
    auto Ag = [&](int kt, int h) { return Abase + (size_t)kt * 128 + (size_t)(h * 128) * rowb; };
    auto Bg = [&](int kt, int h) { return Bbase + (size_t)kt * 128 + (size_t)(h * 128) * rowb; };

    // fragment-read addressing (swizzled)
    const int arow = (wr * 64  + (lane & 15)) * 128;
    const int brow = (wc * 128 + (lane & 15)) * 128;
    const int csw0 = (((lane >> 4) * 16))      ^ ((lane & 7) << 4);
    const int csw1 = (((lane >> 4) * 16) + 64) ^ ((lane & 7) << 4);

    f32x4 acc[4][8];
#pragma unroll
    for (int mi = 0; mi < 4; ++mi)
#pragma unroll
        for (int ni = 0; ni < 8; ++ni)
            acc[mi][ni] = (f32x4){0.f, 0.f, 0.f, 0.f};

    bf16x8 a0[4], a1[4], bA[4], bB[4];

    // ---- prologue: A(0),B(0),A(1),B(1) = 16 loads; oldest 8 (tile0) drained ----
    stageHalf(Ag(0, 0), (char*)lds + 0);
    stageHalf(Ag(0, 1), (char*)lds + 16384);
    stageHalf(Bg(0, 0), (char*)lds + B0OFF);
    stageHalf(Bg(0, 1), (char*)lds + B0OFF + 16384);
    if (NT > 1) {
        stageHalf(Ag(1, 0), (char*)lds + 32768);
        stageHalf(Ag(1, 1), (char*)lds + 32768 + 16384);
        stageHalf(Bg(1, 0), (char*)lds + B0OFF + 32768);
        stageHalf(Bg(1, 1), (char*)lds + B0OFF + 32768 + 16384);
        asm volatile("s_waitcnt vmcnt(8)" ::: "memory");
    } else {
        asm volatile("s_waitcnt vmcnt(0)" ::: "memory");
    }
    __builtin_amdgcn_sched_barrier(0);
    asm volatile("s_barrier" ::: "memory");
    // R0 of tile 0: a0 (kk0) + bA (fn0-3, kk0)
    {
        const char* Al = (const char*)lds;
        const char* Bl = (const char*)lds + B0OFF;
#pragma unroll
        for (int fm = 0; fm < 4; ++fm) a0[fm] = *(const bf16x8*)(Al + arow + fm * 2048 + csw0);
#pragma unroll
        for (int fn = 0; fn < 4; ++fn) bA[fn] = *(const bf16x8*)(Bl + brow + fn * 2048 + csw0);
    }

    int aoff = 0;                                // Abuf byte offset of tile kt
    int bcur = B0OFF, bnxt = B0OFF + 32768, bnn = B0OFF + 65536;

    for (int kt = 0; kt < NT; ++kt) {
        const char* Al = (const char*)lds + aoff;
        const char* Bl = (const char*)lds + bcur;
        char* Bs2 = (char*)lds + bnn;            // stage B(kt+2) here
        char* As2 = (char*)lds + aoff;           // stage A(kt+2) here (same Abuf)

        // ---- p0: stage B0(t+2); read R1 {a1 kk1, bB fn4-7 kk0}; MFMA a0 x bA ----
        if (kt + 2 < NT) stageHalf(Bg(kt + 2, 0), Bs2);
#pragma unroll
        for (int fm = 0; fm < 4; ++fm) a1[fm] = *(const bf16x8*)(Al + arow + fm * 2048 + csw1);
#pragma unroll
        for (int fn = 0; fn < 4; ++fn) bB[fn] = *(const bf16x8*)(Bl + brow + (fn + 4) * 2048 + csw0);
        __builtin_amdgcn_s_setprio(1);
#pragma unroll
        for (int fm = 0; fm < 4; ++fm)
#pragma unroll
            for (int fn = 0; fn < 4; ++fn)
                acc[fm][fn] = __builtin_amdgcn_mfma_f32_16x16x32_bf16(a0[fm], bA[fn], acc[fm][fn], 0, 0, 0);
        __builtin_amdgcn_s_setprio(0);

        // ---- p1: stage B1(t+2); read R2 {bA <- fn0-3 kk1}; MFMA a0 x bB; MID ----
        if (kt + 2 < NT) stageHalf(Bg(kt + 2, 1), Bs2 + 16384);
#pragma unroll
        for (int fn = 0; fn < 4; ++fn) bA[fn] = *(const bf16x8*)(Bl + brow + fn * 2048 + csw1);
        __builtin_amdgcn_s_setprio(1);
#pragma unroll
        for (int fm = 0; fm < 4; ++fm)
#pragma unroll
            for (int fn = 0; fn < 4; ++fn)
                acc[fm][fn + 4] = __builtin_amdgcn_mfma_f32_16x16x32_bf16(a0[fm], bB[fn], acc[fm][fn + 4], 0, 0, 0);
        __builtin_amdgcn_s_setprio(0);
        asm volatile("s_waitcnt lgkmcnt(0)" ::: "memory");   // all A(t)-reads + old prefetch landed
        asm volatile("s_barrier" ::: "memory");              // MID: A-region handoff

        // ---- p2: stage A0(t+2); read R3 {bB <- fn4-7 kk1}; MFMA a1 x bA ----
        if (kt + 2 < NT) stageHalf(Ag(kt + 2, 0), As2);
#pragma unroll
        for (int fn = 0; fn < 4; ++fn) bB[fn] = *(const bf16x8*)(Bl + brow + (fn + 4) * 2048 + csw1);
        __builtin_amdgcn_s_setprio(1);
#pragma unroll
        for (int fm = 0; fm < 4; ++fm)
#pragma unroll
            for (int fn = 0; fn < 4; ++fn)
                acc[fm][fn] = __builtin_amdgcn_mfma_f32_16x16x32_bf16(a1[fm], bA[fn], acc[fm][fn], 0, 0, 0);
        __builtin_amdgcn_s_setprio(0);

        // ---- p3: stage A1(t+2); vmcnt(8); B3; read R0'(t+1); MFMA a1 x bB; END ----
        if (kt + 2 < NT) stageHalf(Ag(kt + 2, 1), As2 + 16384);
        if (kt + 1 < NT) {
            if (kt + 2 < NT) { asm volatile("s_waitcnt vmcnt(8)" ::: "memory"); }
            else             { asm volatile("s_waitcnt vmcnt(0)" ::: "memory"); }
            __builtin_amdgcn_sched_barrier(0);
            asm volatile("s_barrier" ::: "memory");          // B3: globalize vmcnt ->
                                                             // tile t+1 fully landed
            const char* nAl = (const char*)lds + (aoff ^ 32768);
            const char* nBl = (const char*)lds + bnxt;
#pragma unroll
            for (int fm = 0; fm < 4; ++fm) a0[fm] = *(const bf16x8*)(nAl + arow + fm * 2048 + csw0);
#pragma unroll
            for (int fn = 0; fn < 4; ++fn) bA[fn] = *(const bf16x8*)(nBl + brow + fn * 2048 + csw0);
        }
        __builtin_amdgcn_s_setprio(1);
#pragma unroll
        for (int fm = 0; fm < 4; ++fm)
#pragma unroll
            for (int fn = 0; fn < 4; ++fn)
                acc[fm][fn + 4] = __builtin_amdgcn_mfma_f32_16x16x32_bf16(a1[fm], bB[fn], acc[fm][fn + 4], 0, 0, 0);
        __builtin_amdgcn_s_setprio(0);
        asm volatile("s_barrier" ::: "memory");              // END: B-region handoff + swap

        aoff ^= 32768;
        const int tmp = bcur; bcur = bnxt; bnxt = bnn; bnn = tmp;
    }

    // epilogue: out = acc*scale + bias ; C/D layout col=lane&15, row=(lane>>4)*4+i
    const float scale = *wscale;
    const int orow0 = bm * 256 + wr * 64  + ((lane >> 4) << 2);
    const int ocol0 = bn * 256 + wc * 128 + (lane & 15);
#pragma unroll
    for (int fn = 0; fn < 8; ++fn) {
        const int col = ocol0 + 16 * fn;
        const float bb = bias[col];
#pragma unroll
        for (int fm = 0; fm < 4; ++fm) {
            const int row0 = orow0 + 16 * fm;
#pragma unroll
            for (int i = 0; i < 4; ++i)
                out[(size_t)(row0 + i) * N + col] = acc[fm][fn][i] * scale + bb;
        }
    }
}

// ---------- fallback: round-2 fused kernel (passes; used only if ws too small) ----------
__device__ __forceinline__ int swz(int row, int byte_in_row) {
    return row * 128 + (byte_in_row ^ ((row & 7) << 4));
}

__global__ __launch_bounds__(256) void qlinear_fused_kernel(
    const float* __restrict__ X, const int* __restrict__ W,
    const float* __restrict__ wscale, const float* __restrict__ bias,
    float* __restrict__ out, int M, int N, int K)
{
    __shared__ unsigned char smem[32768];

    const int t    = threadIdx.x;
    const int lane = t & 63;
    const int wid  = t >> 6;
    const int wr   = wid >> 1;
    const int wc   = wid & 1;

    const int ntn = N >> 7;
    const int bm  = blockIdx.x / ntn;
    const int bn  = blockIdx.x % ntn;
    const int NT  = K >> 6;

    const float* Ab = X + (size_t)bm * 128 * K;
    const int*   Bb = W + (size_t)bn * 128 * K;

    const int srow = t >> 4, sc4 = t & 15;

    f32x4 av[8];
    i32x4 bv[8];

    auto loadAB = [&](int kt) {
        const float* Ap = Ab + kt * 64 + sc4 * 4;
#pragma unroll
        for (int l = 0; l < 8; ++l)
            av[l] = *(const f32x4*)(Ap + (size_t)(srow + 16 * l) * K);
        const int* Bp = Bb + kt * 64 + sc4 * 4;
#pragma unroll
        for (int l = 0; l < 8; ++l)
            bv[l] = *(const i32x4*)(Bp + (size_t)(srow + 16 * l) * K);
    };

    auto writeAB = [&]() {
#pragma unroll
        for (int l = 0; l < 8; ++l) {
            const int row = srow + 16 * l;
            u32x2 pk;
            pk[0] = f2bf(av[l][0]) | (f2bf(av[l][1]) << 16);
            pk[1] = f2bf(av[l][2]) | (f2bf(av[l][3]) << 16);
            *(u32x2*)(smem + swz(row, sc4 * 8)) = pk;
        }
#pragma unroll
        for (int l = 0; l < 8; ++l) {
            const int row = srow + 16 * l;
            u32x2 pk;
            pk[0] = f2bf((float)bv[l][0]) | (f2bf((float)bv[l][1]) << 16);
            pk[1] = f2bf((float)bv[l][2]) | (f2bf((float)bv[l][3]) << 16);
            *(u32x2*)(smem + 16384 + swz(row, sc4 * 8)) = pk;
        }
    };

    f32x4 acc[4][4];
#pragma unroll
    for (int mi = 0; mi < 4; ++mi)
#pragma unroll
        for (int ni = 0; ni < 4; ++ni)
            acc[mi][ni] = (f32x4){0.f, 0.f, 0.f, 0.f};

    const int kbyte = (lane >> 4) * 16;
    const int afr   = wr * 64 + (lane & 15);
    const int bfr   = wc * 64 + (lane & 15);

    loadAB(0);

    for (int kt = 0; kt < NT; ++kt) {
        writeAB();
        __syncthreads();
        if (kt + 1 < NT) loadAB(kt + 1);
#pragma unroll
        for (int kk = 0; kk < 2; ++kk) {
            bf16x8 a[4], b[4];
#pragma unroll
            for (int mi = 0; mi < 4; ++mi)
                a[mi] = *(const bf16x8*)(smem + swz(afr + 16 * mi, kk * 64 + kbyte));
#pragma unroll
            for (int ni = 0; ni < 4; ++ni)
                b[ni] = *(const bf16x8*)(smem + 16384 + swz(bfr + 16 * ni, kk * 64 + kbyte));
#pragma unroll
            for (int mi = 0; mi < 4; ++mi)
#pragma unroll
                for (int ni = 0; ni < 4; ++ni)
                    acc[mi][ni] = __builtin_amdgcn_mfma_f32_16x16x32_bf16(
                        a[mi], b[ni], acc[mi][ni], 0, 0, 0);
        }
        __syncthreads();
    }

    const float scale = *wscale;
    const int orow0 = bm * 128 + wr * 64 + ((lane >> 4) << 2);
    const int ocol0 = bn * 128 + wc * 64 + (lane & 15);
#pragma unroll
    for (int ni = 0; ni < 4; ++ni) {
        const int col = ocol0 + 16 * ni;
        const float bb = bias[col];
#pragma unroll
        for (int mi = 0; mi < 4; ++mi) {
            const int row0 = orow0 + 16 * mi;
#pragma unroll
            for (int i = 0; i < 4; ++i)
                out[(size_t)(row0 + i) * N + col] = acc[mi][ni][i] * scale + bb;
        }
    }
}

extern "C" void kernel_launch(void* const* d_in, const int* in_sizes, int n_in,
                              void* d_out, int out_size, void* d_ws, size_t ws_size,
                              hipStream_t stream) {
    const float* x      = (const float*)d_in[0];
    const int*   w      = (const int*)d_in[1];      // int inputs arrive as int32
    const float* wscale = (const float*)d_in[2];
    const float* bias   = (const float*)d_in[3];
    float*       out    = (float*)d_out;

    const int DOUT = in_sizes[3];
    const int DIN  = in_sizes[1] / DOUT;
    const int M    = in_sizes[0] / DIN;

    const size_t xb_bytes = (size_t)M * DIN * 2;
    const size_t wb_bytes = (size_t)DOUT * DIN * 2;

    if (ws_size >= xb_bytes + wb_bytes && (M % 256) == 0 && (DOUT % 256) == 0
        && (DIN % 64) == 0 && (DIN / 64) >= 2) {
        unsigned short* xb = (unsigned short*)d_ws;
        unsigned short* wb = (unsigned short*)((char*)d_ws + xb_bytes);

        const long long nx8 = (long long)M * DIN / 8;
        const long long nw8 = (long long)DOUT * DIN / 8;
        convert_x_kernel<<<2048, 256, 0, stream>>>(x, xb, nx8);
        convert_w_kernel<<<2048, 256, 0, stream>>>(w, wb, nw8);

        dim3 grid((M / 256) * (DOUT / 256));
        gemm256_kernel<<<grid, 512, 0, stream>>>(xb, wb, wscale, bias, out, M, DOUT, DIN);
    } else {
        dim3 grid((M / 128) * (DOUT / 128));
        qlinear_fused_kernel<<<grid, 256, 0, stream>>>(x, w, wscale, bias, out, M, DOUT, DIN);
    }
}

// Round 9
// 280.392 us; speedup vs baseline: 1.8263x; 1.0160x over previous
//
#include <hip/hip_runtime.h>
#include <hip/hip_bf16.h>

typedef __attribute__((ext_vector_type(8))) short bf16x8;
typedef __attribute__((ext_vector_type(4))) float f32x4;
typedef __attribute__((ext_vector_type(4))) int i32x4;
typedef __attribute__((ext_vector_type(2))) unsigned int u32x2;
typedef __attribute__((ext_vector_type(4))) unsigned int u32x4;

// RNE fp32 -> bf16 bits (inputs finite; no NaN handling needed)
__device__ __forceinline__ unsigned int f2bf(float f) {
    union { float f; unsigned int u; } v; v.f = f;
    unsigned int u = v.u;
    u += 0x7FFFu + ((u >> 16) & 1u);
    return u >> 16;
}

__device__ __forceinline__ void gl_lds16(const void* gptr, void* lptr) {
    __builtin_amdgcn_global_load_lds(
        (const __attribute__((address_space(1))) unsigned int*)gptr,
        (__attribute__((address_space(3))) unsigned int*)lptr, 16, 0, 0);
}

// ---------- pre-pass converts ----------
__global__ __launch_bounds__(256) void convert_x_kernel(
    const float* __restrict__ x, unsigned short* __restrict__ xb, long long n8)
{
    long long i = (long long)blockIdx.x * blockDim.x + threadIdx.x;
    const long long stride = (long long)gridDim.x * blockDim.x;
    for (; i < n8; i += stride) {
        const f32x4* p = (const f32x4*)(x + i * 8);
        f32x4 v0 = p[0], v1 = p[1];
        u32x4 q;
        q[0] = f2bf(v0[0]) | (f2bf(v0[1]) << 16);
        q[1] = f2bf(v0[2]) | (f2bf(v0[3]) << 16);
        q[2] = f2bf(v1[0]) | (f2bf(v1[1]) << 16);
        q[3] = f2bf(v1[2]) | (f2bf(v1[3]) << 16);
        *(u32x4*)(xb + i * 8) = q;
    }
}

__global__ __launch_bounds__(256) void convert_w_kernel(
    const int* __restrict__ w, unsigned short* __restrict__ wb, long long n8)
{
    long long i = (long long)blockIdx.x * blockDim.x + threadIdx.x;
    const long long stride = (long long)gridDim.x * blockDim.x;
    for (; i < n8; i += stride) {
        const i32x4* p = (const i32x4*)(w + i * 8);
        i32x4 v0 = p[0], v1 = p[1];
        u32x4 q;   // int8 values are exact in bf16
        q[0] = f2bf((float)v0[0]) | (f2bf((float)v0[1]) << 16);
        q[1] = f2bf((float)v0[2]) | (f2bf((float)v0[3]) << 16);
        q[2] = f2bf((float)v1[0]) | (f2bf((float)v1[1]) << 16);
        q[3] = f2bf((float)v1[2]) | (f2bf((float)v1[3]) << 16);
        *(u32x4*)(wb + i * 8) = q;
    }
}

// ---------- 256x256 pipelined GEMM, A tribuf / B dbuf (T1+T2+T3+T4+T5) ----------
// 512 thr = 8 waves in 4Mx2N; per-wave out 64x128. BK=64.
// LDS 160KB: A tribuf 3x32KB @ {0,32768,65536}; B dbuf 2x32KB @ {98304,131072}.
// Phase p issues phase p+1's ds_reads; MFMAs run on regs read last phase.
// Stage rotation during tile t: p0/p1 -> B(t+1) halves [other B buf, held
// B(t-1), fully read + operand-waited before END(t-1)]; p2/p3 -> A(t+2)
// halves [Abuf[(t+2)%3], held A(t-1), last read at p0(t-1), landed before
// p1(t-1) MFMA, ordered before any t-stage by END(t-1)].
// ONLY 2 barriers/tile, no wave-global lgkmcnt(0) (r8 post-mortem: the MID
// lgkmcnt(0)+barrier lockstep was the dominant per-tile stall):
//   B3  (p3, after vmcnt): globalizes per-wave vmcnt -> tile t+1 (A staged in
//       t-1, B staged in t) DMA-complete across ALL waves before prefetch-read.
//   END (end p3): all B(t)/A(t) reads operand-waited -> next tile may DMA.
// vmcnt(4) = A(t+2)'s own 4 stage-loads may remain in flight; B(t+1)+A(t+1)
// must be drained.
__global__ __launch_bounds__(512, 2) void gemm256_kernel(
    const unsigned short* __restrict__ A, const unsigned short* __restrict__ Bw,
    const float* __restrict__ wscale, const float* __restrict__ bias,
    float* __restrict__ out, int M, int N, int K)
{
    __shared__ unsigned char lds[163840];
    const int B0OFF = 98304;

    const int tid  = threadIdx.x;
    const int lane = tid & 63;
    const int wid  = tid >> 6;
    const int wr   = wid >> 1;   // 0..3 -> 64 output rows each
    const int wc   = wid & 1;    // 0..1 -> 128 output cols each

    const int ntn = N >> 8;
    const int nwg = gridDim.x;
    int bid = blockIdx.x;
    if ((nwg & 7) == 0) {                       // XCD-aware swizzle (T1)
        const int cpx = nwg >> 3;
        bid = (bid & 7) * cpx + (bid >> 3);
    }
    const int bm = bid / ntn;
    const int bn = bid % ntn;
    const int NT = K >> 6;

    const char* Abase = (const char*)(A  + (size_t)bm * 256 * K);
    const char* Bbase = (const char*)(Bw + (size_t)bn * 256 * K);
    const size_t rowb = (size_t)K * 2;

    // staging: half-tile = 128 rows x 128B (16KB); 2 gl_lds per thread.
    // Linear LDS dest; source column pre-swizzled (rule 21).
    const int s_colb = (((lane & 7) ^ (lane >> 3)) << 4);
    const int s_rsub = wid * 8 + (lane >> 3);
    const int s_ldso = wid * 1024 + lane * 16;

    auto stageHalf = [&](const char* gRowBase, char* lhalf) {
#pragma unroll
        for (int q = 0; q < 2; ++q)
            gl_lds16(gRowBase + (size_t)(q * 64 + s_rsub) * rowb + s_colb,
                     lhalf + q * 8192 + s_ldso);
    };
    auto Ag = [&](int kt, int h) { return Abase + (size_t)kt * 128 + (size_t)(h * 128) * rowb; };
    auto Bg = [&](int kt, int h) { return Bbase + (size_t)kt * 128 + (size_t)(h * 128) * rowb; };

    // fragment-read addressing (swizzled)
    const int arow = (wr * 64  + (lane & 15)) * 128;
    const int brow = (wc * 128 + (lane & 15)) * 128;
    const int csw0 = (((lane >> 4) * 16))      ^ ((lane & 7) << 4);
    const int csw1 = (((lane >> 4) * 16) + 64) ^ ((lane & 7) << 4);

    f32x4 acc[4][8];
#pragma unroll
    for (int mi = 0; mi < 4; ++mi)
#pragma unroll
        for (int ni = 0; ni < 8; ++ni)
            acc[mi][ni] = (f32x4){0.f, 0.f, 0.f, 0.f};

    bf16x8 a0[4], a1[4], bA[4], bB[4];

    // ---- prologue: A(0)->Abuf0, B(0)->Bbuf0, A(1)->Abuf1; tile0 must land ----
    stageHalf(Ag(0, 0), (char*)lds + 0);
    stageHalf(Ag(0, 1), (char*)lds + 16384);
    stageHalf(Bg(0, 0), (char*)lds + B0OFF);
    stageHalf(Bg(0, 1), (char*)lds + B0OFF + 16384);
    if (NT > 1) {
        stageHalf(Ag(1, 0), (char*)lds + 32768);
        stageHalf(Ag(1, 1), (char*)lds + 32768 + 16384);
        asm volatile("s_waitcnt vmcnt(4)" ::: "memory");   // A(1) may stay in flight
    } else {
        asm volatile("s_waitcnt vmcnt(0)" ::: "memory");
    }
    __builtin_amdgcn_sched_barrier(0);
    asm volatile("s_barrier" ::: "memory");
    // R0 of tile 0: a0 (kk0) + bA (fn0-3, kk0)
    {
        const char* Al = (const char*)lds;
        const char* Bl = (const char*)lds + B0OFF;
#pragma unroll
        for (int fm = 0; fm < 4; ++fm) a0[fm] = *(const bf16x8*)(Al + arow + fm * 2048 + csw0);
#pragma unroll
        for (int fn = 0; fn < 4; ++fn) bA[fn] = *(const bf16x8*)(Bl + brow + fn * 2048 + csw0);
    }

    int acur = 0, anxt = 32768, ann = 65536;   // A tribuf rotation
    int bcur = B0OFF, both = B0OFF + 32768;    // B dbuf

    for (int kt = 0; kt < NT; ++kt) {
        const char* Al = (const char*)lds + acur;
        const char* Bl = (const char*)lds + bcur;
        char* Bs  = (char*)lds + both;          // B(t+1) dest (other B buf)
        char* As2 = (char*)lds + ann;           // A(t+2) dest (A(t-1)'s buf)

        // ---- p0: stage B0(t+1); read R1 {a1 kk1, bB fn4-7 kk0}; MFMA a0 x bA ----
        if (kt + 1 < NT) stageHalf(Bg(kt + 1, 0), Bs);
#pragma unroll
        for (int fm = 0; fm < 4; ++fm) a1[fm] = *(const bf16x8*)(Al + arow + fm * 2048 + csw1);
#pragma unroll
        for (int fn = 0; fn < 4; ++fn) bB[fn] = *(const bf16x8*)(Bl + brow + (fn + 4) * 2048 + csw0);
        __builtin_amdgcn_s_setprio(1);
#pragma unroll
        for (int fm = 0; fm < 4; ++fm)
#pragma unroll
            for (int fn = 0; fn < 4; ++fn)
                acc[fm][fn] = __builtin_amdgcn_mfma_f32_16x16x32_bf16(a0[fm], bA[fn], acc[fm][fn], 0, 0, 0);
        __builtin_amdgcn_s_setprio(0);

        // ---- p1: stage B1(t+1); read R2 {bA <- fn0-3 kk1}; MFMA a0 x bB ----
        if (kt + 1 < NT) stageHalf(Bg(kt + 1, 1), Bs + 16384);
#pragma unroll
        for (int fn = 0; fn < 4; ++fn) bA[fn] = *(const bf16x8*)(Bl + brow + fn * 2048 + csw1);
        __builtin_amdgcn_s_setprio(1);
#pragma unroll
        for (int fm = 0; fm < 4; ++fm)
#pragma unroll
            for (int fn = 0; fn < 4; ++fn)
                acc[fm][fn + 4] = __builtin_amdgcn_mfma_f32_16x16x32_bf16(a0[fm], bB[fn], acc[fm][fn + 4], 0, 0, 0);
        __builtin_amdgcn_s_setprio(0);
        // (no MID barrier: A(t+2) goes to A(t-1)'s buffer, freed via END(t-1))

        // ---- p2: stage A0(t+2); read R3 {bB <- fn4-7 kk1}; MFMA a1 x bA ----
        if (kt + 2 < NT) stageHalf(Ag(kt + 2, 0), As2);
#pragma unroll
        for (int fn = 0; fn < 4; ++fn) bB[fn] = *(const bf16x8*)(Bl + brow + (fn + 4) * 2048 + csw1);
        __builtin_amdgcn_s_setprio(1);
#pragma unroll
        for (int fm = 0; fm < 4; ++fm)
#pragma unroll
            for (int fn = 0; fn < 4; ++fn)
                acc[fm][fn] = __builtin_amdgcn_mfma_f32_16x16x32_bf16(a1[fm], bA[fn], acc[fm][fn], 0, 0, 0);
        __builtin_amdgcn_s_setprio(0);

        // ---- p3: stage A1(t+2); vmcnt(4); B3; read R0'(t+1); MFMA a1 x bB; END ----
        if (kt + 2 < NT) stageHalf(Ag(kt + 2, 1), As2 + 16384);
        if (kt + 1 < NT) {
            if (kt + 2 < NT) { asm volatile("s_waitcnt vmcnt(4)" ::: "memory"); }
            else             { asm volatile("s_waitcnt vmcnt(0)" ::: "memory"); }
            __builtin_amdgcn_sched_barrier(0);
            asm volatile("s_barrier" ::: "memory");          // B3: globalize vmcnt ->
                                                             // tile t+1 fully landed
            const char* nAl = (const char*)lds + anxt;
            const char* nBl = (const char*)lds + both;
#pragma unroll
            for (int fm = 0; fm < 4; ++fm) a0[fm] = *(const bf16x8*)(nAl + arow + fm * 2048 + csw0);
#pragma unroll
            for (int fn = 0; fn < 4; ++fn) bA[fn] = *(const bf16x8*)(nBl + brow + fn * 2048 + csw0);
        }
        __builtin_amdgcn_s_setprio(1);
#pragma unroll
        for (int fm = 0; fm < 4; ++fm)
#pragma unroll
            for (int fn = 0; fn < 4; ++fn)
                acc[fm][fn + 4] = __builtin_amdgcn_mfma_f32_16x16x32_bf16(a1[fm], bB[fn], acc[fm][fn + 4], 0, 0, 0);
        __builtin_amdgcn_s_setprio(0);
        asm volatile("s_barrier" ::: "memory");              // END: region handoff + swap

        const int at = acur; acur = anxt; anxt = ann; ann = at;
        const int bt = bcur; bcur = both; both = bt;
    }

    // epilogue: out = acc*scale + bias ; C/D layout col=lane&15, row=(lane>>4)*4+i
    const float scale = *wscale;
    const int orow0 = bm * 256 + wr * 64  + ((lane >> 4) << 2);
    const int ocol0 = bn * 256 + wc * 128 + (lane & 15);
#pragma unroll
    for (int fn = 0; fn < 8; ++fn) {
        const int col = ocol0 + 16 * fn;
        const float bb = bias[col];
#pragma unroll
        for (int fm = 0; fm < 4; ++fm) {
            const int row0 = orow0 + 16 * fm;
#pragma unroll
            for (int i = 0; i < 4; ++i)
                out[(size_t)(row0 + i) * N + col] = acc[fm][fn][i] * scale + bb;
        }
    }
}

// ---------- fallback: round-2 fused kernel (passes; used only if ws too small) ----------
__device__ __forceinline__ int swz(int row, int byte_in_row) {
    return row * 128 + (byte_in_row ^ ((row & 7) << 4));
}

__global__ __launch_bounds__(256) void qlinear_fused_kernel(
    const float* __restrict__ X, const int* __restrict__ W,
    const float* __restrict__ wscale, const float* __restrict__ bias,
    float* __restrict__ out, int M, int N, int K)
{
    __shared__ unsigned char smem[32768];

    const int t    = threadIdx.x;
    const int lane = t & 63;
    const int wid  = t >> 6;
    const int wr   = wid >> 1;
    const int wc   = wid & 1;

    const int ntn = N >> 7;
    const int bm  = blockIdx.x / ntn;
    const int bn  = blockIdx.x % ntn;
    const int NT  = K >> 6;

    const float* Ab = X + (size_t)bm * 128 * K;
    const int*   Bb = W + (size_t)bn * 128 * K;

    const int srow = t >> 4, sc4 = t & 15;

    f32x4 av[8];
    i32x4 bv[8];

    auto loadAB = [&](int kt) {
        const float* Ap = Ab + kt * 64 + sc4 * 4;
#pragma unroll
        for (int l = 0; l < 8; ++l)
            av[l] = *(const f32x4*)(Ap + (size_t)(srow + 16 * l) * K);
        const int* Bp = Bb + kt * 64 + sc4 * 4;
#pragma unroll
        for (int l = 0; l < 8; ++l)
            bv[l] = *(const i32x4*)(Bp + (size_t)(srow + 16 * l) * K);
    };

    auto writeAB = [&]() {
#pragma unroll
        for (int l = 0; l < 8; ++l) {
            const int row = srow + 16 * l;
            u32x2 pk;
            pk[0] = f2bf(av[l][0]) | (f2bf(av[l][1]) << 16);
            pk[1] = f2bf(av[l][2]) | (f2bf(av[l][3]) << 16);
            *(u32x2*)(smem + swz(row, sc4 * 8)) = pk;
        }
#pragma unroll
        for (int l = 0; l < 8; ++l) {
            const int row = srow + 16 * l;
            u32x2 pk;
            pk[0] = f2bf((float)bv[l][0]) | (f2bf((float)bv[l][1]) << 16);
            pk[1] = f2bf((float)bv[l][2]) | (f2bf((float)bv[l][3]) << 16);
            *(u32x2*)(smem + 16384 + swz(row, sc4 * 8)) = pk;
        }
    };

    f32x4 acc[4][4];
#pragma unroll
    for (int mi = 0; mi < 4; ++mi)
#pragma unroll
        for (int ni = 0; ni < 4; ++ni)
            acc[mi][ni] = (f32x4){0.f, 0.f, 0.f, 0.f};

    const int kbyte = (lane >> 4) * 16;
    const int afr   = wr * 64 + (lane & 15);
    const int bfr   = wc * 64 + (lane & 15);

    loadAB(0);

    for (int kt = 0; kt < NT; ++kt) {
        writeAB();
        __syncthreads();
        if (kt + 1 < NT) loadAB(kt + 1);
#pragma unroll
        for (int kk = 0; kk < 2; ++kk) {
            bf16x8 a[4], b[4];
#pragma unroll
            for (int mi = 0; mi < 4; ++mi)
                a[mi] = *(const bf16x8*)(smem + swz(afr + 16 * mi, kk * 64 + kbyte));
#pragma unroll
            for (int ni = 0; ni < 4; ++ni)
                b[ni] = *(const bf16x8*)(smem + 16384 + swz(bfr + 16 * ni, kk * 64 + kbyte));
#pragma unroll
            for (int mi = 0; mi < 4; ++mi)
#pragma unroll
                for (int ni = 0; ni < 4; ++ni)
                    acc[mi][ni] = __builtin_amdgcn_mfma_f32_16x16x32_bf16(
                        a[mi], b[ni], acc[mi][ni], 0, 0, 0);
        }
        __syncthreads();
    }

    const float scale = *wscale;
    const int orow0 = bm * 128 + wr * 64 + ((lane >> 4) << 2);
    const int ocol0 = bn * 128 + wc * 64 + (lane & 15);
#pragma unroll
    for (int ni = 0; ni < 4; ++ni) {
        const int col = ocol0 + 16 * ni;
        const float bb = bias[col];
#pragma unroll
        for (int mi = 0; mi < 4; ++mi) {
            const int row0 = orow0 + 16 * mi;
#pragma unroll
            for (int i = 0; i < 4; ++i)
                out[(size_t)(row0 + i) * N + col] = acc[mi][ni][i] * scale + bb;
        }
    }
}

extern "C" void kernel_launch(void* const* d_in, const int* in_sizes, int n_in,
                              void* d_out, int out_size, void* d_ws, size_t ws_size,
                              hipStream_t stream) {
    const float* x      = (const float*)d_in[0];
    const int*   w      = (const int*)d_in[1];      // int inputs arrive as int32
    const float* wscale = (const float*)d_in[2];
    const float* bias   = (const float*)d_in[3];
    float*       out    = (float*)d_out;

    const int DOUT = in_sizes[3];
    const int DIN  = in_sizes[1] / DOUT;
    const int M    = in_sizes[0] / DIN;

    const size_t xb_bytes = (size_t)M * DIN * 2;
    const size_t wb_bytes = (size_t)DOUT * DIN * 2;

    if (ws_size >= xb_bytes + wb_bytes && (M % 256) == 0 && (DOUT % 256) == 0
        && (DIN % 64) == 0 && (DIN / 64) >= 2) {
        unsigned short* xb = (unsigned short*)d_ws;
        unsigned short* wb = (unsigned short*)((char*)d_ws + xb_bytes);

        const long long nx8 = (long long)M * DIN / 8;
        const long long nw8 = (long long)DOUT * DIN / 8;
        convert_x_kernel<<<2048, 256, 0, stream>>>(x, xb, nx8);
        convert_w_kernel<<<2048, 256, 0, stream>>>(w, wb, nw8);

        dim3 grid((M / 256) * (DOUT / 256));
        gemm256_kernel<<<grid, 512, 0, stream>>>(xb, wb, wscale, bias, out, M, DOUT, DIN);
    } else {
        dim3 grid((M / 128) * (DOUT / 128));
        qlinear_fused_kernel<<<grid, 256, 0, stream>>>(x, w, wscale, bias, out, M, DOUT, DIN);
    }
}